// Round 5
// baseline (188.216 us; speedup 1.0000x reference)
//
#include <hip/hip_runtime.h>
#include <math.h>

// DCN v2: B=8, C=128, O=128, H=W=64, k=3, dil=1, dg=1, stride=1, pad=1.
// R13: structural split. R12 measurements showed the fused kernel runs ~3x
// above its throughput floor (MFMA 6%, VALU 10%, LDS ~30%, HBM 5% - nothing
// saturated): the 2-blocks/CU barrier-convoy structure is the bottleneck,
// and instruction-level fixes (R10-R12) moved 72 -> 70 us only.
// New path (gated on ws_size >= 84.2 MB):
//   1) dcn_im2col: proven meta+band+f16-interp code, writes sampled
//      fragments to workspace S[b][px=4096][k'=1280] f16. grid 1024
//      (4 granules/block), no MFMA coupling.
//   2) dcn_gemm: NO barriers in main loop. B-frags read directly from S
//      (16B global loads, 4 mrow-waves share px-rows via L1), A-frags
//      from L2-resident wh with full-granule prefetch (register budget is
//      free now). HBM-bound ~100 MB -> ~16 us.
// Fallbacks kept verbatim: R12 fused kernel (ws >= 328 KB), fp32 (no ws).
constexpr int Bn = 8, Cn = 128, On = 128, Hn = 64, Wn = 64;
constexpr int KK = 9, PAD = 1;
constexpr int BDIM = 512;                 // 8 waves
constexpr int PXB  = 64;                  // full row per block
constexpr int CG = 16, NG = Cn / CG;      // 8 channel granules
constexpr int KG = 160, KTOT = NG * KG;   // 1280 (144 real + 16 pad per granule)
constexpr int BANDH = 11;                 // band rows (h-5 .. h+5)
constexpr int RST  = 68;                  // pband row stride (dwords)
constexpr int XSTP = 756;                 // pband pair stride (dwords), 16B-aligned
constexpr int AST  = 84;                  // ash px stride (dwords), 16B-aligned
constexpr int ME   = KK * PXB;            // 576 sampling elements
constexpr int PB_DW  = 8 * XSTP;          // 6048
constexpr int ASH_DW = PXB * AST;         // 5376
constexpr int SM_DW  = PB_DW + 2 * ASH_DW;// 16800 dwords = 67,200 B
constexpr int BUNITS = BANDH * 128;       // 1408 band load/write units

// ---- split-path workspace layout ----
constexpr int    KRD     = 640;                         // dwords per S px-row (1280 f16)
constexpr size_t S_DW    = (size_t)Bn * 4096 * KRD;     // 20,971,520 dwords
constexpr size_t S_BYTES = S_DW * 4;                    // 83,886,080 B
constexpr size_t WH_BYTES = (size_t)On * KTOT * 2;      // 327,680 B

typedef __attribute__((ext_vector_type(2))) _Float16 h2;      // arithmetic
typedef __attribute__((ext_vector_type(8))) __fp16   f16x8;   // MFMA operand
typedef __attribute__((ext_vector_type(4))) float f32x4;
typedef unsigned short u16;
typedef unsigned int u32;

union UH  { u32 u; h2 h; };
union U4H { uint4 u; f16x8 h; };

__device__ __forceinline__ u32 pkh(float a, float b) {  // low16 = f16(a), RTZ
    union { decltype(__builtin_amdgcn_cvt_pkrtz(0.f, 0.f)) p; u32 u; } t;
    t.p = __builtin_amdgcn_cvt_pkrtz(a, b);
    return t.u;
}
__device__ __forceinline__ h2 bch(u32 w) { UH t; t.u = w; return t.h; }
__device__ __forceinline__ u16 f2h(float f) {           // RNE f32->f16
    union { _Float16 h; u16 u; } v; v.h = (_Float16)f; return v.u;
}

// weight [O][C*9] fp32 -> wh [O][KTOT] f16, k' = g*KG + t*16 + cl.
__global__ void wprep_kernel(const float* __restrict__ w, u16* __restrict__ wh) {
    __shared__ u32 tmpw[KTOT / 2];
    u16* tmp = (u16*)tmpw;
    const int tid = threadIdx.x, o = blockIdx.x;
    if (tid < 64)    // zero pad slices k=144..159 of each granule (dwords 72..79)
        tmpw[(tid >> 3) * 80 + 72 + (tid & 7)] = 0;
    for (int k = tid; k < Cn * KK; k += 256) {
        const int c = k / 9, t = k - 9 * c;
        tmp[(c >> 4) * KG + t * 16 + (c & 15)] = f2h(w[o * (Cn * KK) + k]);
    }
    __syncthreads();
    u32* dst = (u32*)(wh + (size_t)o * KTOT);
    for (int e = tid; e < KTOT / 2; e += 256) dst[e] = tmpw[e];
}

// ---- shared sampling core: gather 16 channels for one (tap,px) element ----
// returns 8 packed-f16 dwords in avp.
__device__ __forceinline__ void sample_core(const u32* __restrict__ pband,
                                            const float* __restrict__ xg,
                                            const uint4 wp, const int2 q,
                                            const int2 ix, u32* avp)
{
    if (!__any((q.x | q.y) < 0)) {           // all corners of wave in band
        const u32* p0 = pband + ix.x;
        const u32* p1 = pband + ix.y;
        const h2 w0 = bch(wp.x), w1 = bch(wp.y), w2 = bch(wp.z), w3 = bch(wp.w);
        #pragma unroll
        for (int c2 = 0; c2 < 8; ++c2) {
            const h2 vt0 = bch(p0[c2 * XSTP]), vt1 = bch(p0[c2 * XSTP + 1]);
            const h2 vb0 = bch(p1[c2 * XSTP]), vb1 = bch(p1[c2 * XSTP + 1]);
            const h2 r = w0 * vt0 + w1 * vt1 + w2 * vb0 + w3 * vb1;
            UH o; o.h = r; avp[c2] = o.u;
        }
    } else {                                  // rare: clamped global reads
        const float fw0 = (float)bch(wp.x)[0], fw1 = (float)bch(wp.y)[0];
        const float fw2 = (float)bch(wp.z)[0], fw3 = (float)bch(wp.w)[0];
        const int qx = q.x < 0 ? ~q.x : q.x;
        const int qy = q.y < 0 ? ~q.y : q.y;
        const int yrx = qx >> 8, yry = qy >> 8;
        const int xx = (qx & 255) - 1, xy = (qy & 255) - 1;
        const int ax0 = max(xx, 0), ax1 = min(xx + 1, Wn - 1);
        const int ay0 = max(xy, 0), ay1 = min(xy + 1, Wn - 1);
        #pragma unroll
        for (int c2 = 0; c2 < 8; ++c2) {
            float v2[2];
            #pragma unroll
            for (int sb = 0; sb < 2; ++sb) {
                const float* gc = xg + ((2 * c2 + sb) << 12);
                const float t0 = gc[yrx * Wn + ax0], t1 = gc[yrx * Wn + ax1];
                const float b0 = gc[yry * Wn + ay0], b1 = gc[yry * Wn + ay1];
                v2[sb] = fmaf(fw0, t0, fmaf(fw1, t1, fmaf(fw2, b0, fw3 * b1)));
            }
            avp[c2] = pkh(v2[0], v2[1]);
        }
    }
}

// fused-path variant: write to LDS ash
__device__ __forceinline__ void do_sample(const u32* __restrict__ pband,
                                          u32* __restrict__ ashW,
                                          const float* __restrict__ xg,
                                          const uint4 wp, const int2 q,
                                          const int2 ix, const int e)
{
    const int t = e >> 6, px = e & 63;
    u32 avp[8];
    sample_core(pband, xg, wp, q, ix, avp);
    u32* d = ashW + px * AST + t * 8;
    *(uint4*)&d[0] = make_uint4(avp[0], avp[1], avp[2], avp[3]);
    *(uint4*)&d[4] = make_uint4(avp[4], avp[5], avp[6], avp[7]);
}

// split-path variant: write to global S (Sg = row base for this (b,h))
__device__ __forceinline__ void do_sample_g(const u32* __restrict__ pband,
                                            u32* __restrict__ Sg,
                                            const float* __restrict__ xg,
                                            const uint4 wp, const int2 q,
                                            const int2 ix, const int e,
                                            const int g)
{
    const int t = e >> 6, px = e & 63;
    u32 avp[8];
    sample_core(pband, xg, wp, q, ix, avp);
    u32* d = Sg + (size_t)px * KRD + g * 80 + t * 8;
    *(uint4*)&d[0] = make_uint4(avp[0], avp[1], avp[2], avp[3]);
    *(uint4*)&d[4] = make_uint4(avp[4], avp[5], avp[6], avp[7]);
}

// ======================= split kernel 1: im2col =======================
// grid 1024: b = bid&7, h = (bid>>3)&63, gset = bid>>9 (granules gset*4..+3)
__global__ __launch_bounds__(BDIM, 4)
void dcn_im2col(const float* __restrict__ x,
                const float* __restrict__ offs,
                const float* __restrict__ mask,
                u32* __restrict__ S32)
{
    __shared__ __align__(16) u32 pband[PB_DW];   // 24,192 B

    const int tid  = threadIdx.x;
    const int b    = blockIdx.x & 7;             // batch <-> XCD affinity
    const int h    = (blockIdx.x >> 3) & 63;
    const int g0   = (blockIdx.x >> 9) * 4;
    const int r0   = min(max(h - 5, 0), Hn - BANDH);
    const int s_px4 = tid & 15, s_pair = (tid >> 4) & 7;
    u32* const Sg = S32 + ((size_t)b * 4096 + h * 64) * KRD;

    float4 bnda[3], bndb[3];
#define BLOAD(GCH) { \
        _Pragma("unroll") \
        for (int it = 0; it < 3; ++it) { \
            const int u = tid + it * BDIM; \
            if (u < BUNITS) { \
                const int row = u >> 7; \
                const float* bp = x + (((size_t)(b * Cn + (GCH) * CG + 2 * s_pair)) << 12) \
                                  + (r0 + row) * Wn + (s_px4 << 2); \
                bnda[it] = *(const float4*)bp; \
                bndb[it] = *(const float4*)(bp + 4096); \
            } \
        } }
#define BWRITE() { \
        _Pragma("unroll") \
        for (int it = 0; it < 3; ++it) { \
            const int u = tid + it * BDIM; \
            if (u < BUNITS) { \
                const int row = u >> 7; \
                u32* d = &pband[s_pair * XSTP + row * RST + 8 + (s_px4 << 2)]; \
                *(uint4*)d = make_uint4( \
                    pkh(bnda[it].x, bndb[it].x), pkh(bnda[it].y, bndb[it].y), \
                    pkh(bnda[it].z, bndb[it].z), pkh(bnda[it].w, bndb[it].w)); \
            } \
        } }

    BLOAD(g0);   // issue first band loads before meta (latency overlap)

    // ---- meta in registers (identical to fused kernel) ----
    uint4 mwp[2]; int2 mq[2]; int2 mi[2];
    #pragma unroll
    for (int it = 0; it < 2; ++it) {
        mwp[it] = make_uint4(0, 0, 0, 0);
        mq[it] = make_int2(r0 << 8, r0 << 8);
        mi[it] = make_int2(7, 7);
        const int e = tid + it * BDIM;
        if (e < ME) {
            const int t = e >> 6, px = e & 63;
            const int ty = t / 3, tx = t - ty * 3;
            const float oy = offs[((b * 18 + 2 * t    ) * Hn + h) * Wn + px];
            const float ox = offs[((b * 18 + 2 * t + 1) * Hn + h) * Wn + px];
            const float m  = mask[((b * KK + t) * Hn + h) * Wn + px];
            const float py = (float)(h - PAD + ty) + oy;
            const float qx = (float)(px - PAD + tx) + ox;
            const float fy = floorf(py), fx = floorf(qx);
            const float wy1 = py - fy, wx1 = qx - fx;
            const float wy0 = 1.f - wy1, wx0 = 1.f - wx1;
            const int y0 = (int)fy, x0 = (int)fx;
            const bool cx0 = (x0 >= 0) && (x0 < Wn);
            const bool cx1 = (x0 >= -1) && (x0 < Wn - 1);
            const float wr[2] = { wy0, wy1 };
            float wout[4]; int qout[2], iout[2];
            #pragma unroll
            for (int j = 0; j < 2; ++j) {
                const int yr = y0 + j;
                const bool rv = (yr >= 0) && (yr < Hn);
                wout[2 * j]     = (rv && cx0) ? wr[j] * wx0 * m : 0.f;
                wout[2 * j + 1] = (rv && cx1) ? wr[j] * wx1 * m : 0.f;
                int qv;
                if (!rv || (!cx0 && !cx1)) qv = r0 << 8;   // junk: w=0, reads pad
                else                       qv = (yr << 8) | (x0 + 1);
                const bool inband = (qv >> 8) >= r0 && (qv >> 8) < r0 + BANDH;
                qout[j] = inband ? qv : ~qv;
                iout[j] = ((qv >> 8) - r0) * RST + (qv & 255) + 7;
            }
            mwp[it] = make_uint4(pkh(wout[0], wout[0]), pkh(wout[1], wout[1]),
                                 pkh(wout[2], wout[2]), pkh(wout[3], wout[3]));
            mq[it] = make_int2(qout[0], qout[1]);
            mi[it] = make_int2(iout[0], iout[1]);
        }
    }

    // ---- zero pband never-written gaps (NaN guard) ----
    if (tid < 416) {     // per pair: dwords 0..7 and 68r+72..75 (r=0..10)
        const int pair = tid / 52, j = tid - pair * 52;
        const int off = (j < 8) ? j : RST * ((j - 8) >> 2) + 72 + ((j - 8) & 3);
        pband[pair * XSTP + off] = 0;
    }
    // ---- zero S k-pad chunks for this block's granules ----
    #pragma unroll
    for (int it = 0; it < 4; ++it) {
        const int u = tid + it * BDIM;        // 0..2047
        const int px = u >> 5, gg = (u >> 3) & 3, j = u & 7;
        Sg[(size_t)px * KRD + (g0 + gg) * 80 + 72 + j] = 0;
    }

    BWRITE();           // band g0 -> pband
    BLOAD(g0 + 1);      // issue next band loads
    __syncthreads();

    const float* xb = x + (((size_t)(b * Cn)) << 12);
    for (int gg = 0; gg < 4; ++gg) {
        const int g = g0 + gg;
        const float* xg = xb + (((size_t)(g * CG)) << 12);
        do_sample_g(pband, Sg, xg, mwp[0], mq[0], mi[0], tid, g);
        if (tid < 64)
            do_sample_g(pband, Sg, xg, mwp[1], mq[1], mi[1], BDIM + tid, g);
        if (gg < 3) {
            __syncthreads();                 // pband reads done
            BWRITE();                        // band (g+1)
            if (gg < 2) BLOAD(g0 + gg + 2);  // issue band (g+2)
            __syncthreads();                 // pband ready
        }
    }
#undef BLOAD
#undef BWRITE
}

// ======================= split kernel 2: barrier-free GEMM =======================
__global__ __launch_bounds__(BDIM, 4)
void dcn_gemm(const u32* __restrict__ S32,
              const u16* __restrict__ wh,
              const float* __restrict__ bias,
              float* __restrict__ out)
{
    __shared__ __align__(16) float tr[128 * 68];   // 34,816 B (epilogue only)

    const int tid = threadIdx.x;
    const int b   = blockIdx.x & 7;
    const int h   = blockIdx.x >> 3;

    const int wv = tid >> 6, ln = tid & 63, quad = ln >> 4, l16 = ln & 15;
    const int mrow = wv >> 1, ncol = wv & 1;            // 4x2 wave tiling
    const u16* wrow0 = wh + (size_t)(mrow * 32 + l16) * KTOT;
    const int npx0 = ncol * 32 + l16, npx1 = npx0 + 16;
    const u32* Srow = S32 + ((size_t)b * 4096 + h * 64) * KRD;
    const u32* r0p = Srow + (size_t)npx0 * KRD;
    const u32* r1p = Srow + (size_t)npx1 * KRD;

    f32x4 acc[2][2];
    #pragma unroll
    for (int mt = 0; mt < 2; ++mt)
        #pragma unroll
        for (int nt = 0; nt < 2; ++nt) acc[mt][nt] = (f32x4){0.f, 0.f, 0.f, 0.f};

    #pragma unroll 1
    for (int g = 0; g < NG; ++g) {
        f16x8 pa[5][2];                      // full-granule A prefetch (40 VGPR)
        const int kgp = g * KG + quad * 8;
        #pragma unroll
        for (int s = 0; s < 5; ++s) {
            pa[s][0] = *(const f16x8*)(wrow0 + kgp + s * 32);
            pa[s][1] = *(const f16x8*)(wrow0 + 16 * KTOT + kgp + s * 32);
        }
        const int kb = g * 80 + quad * 4;
        #pragma unroll
        for (int s = 0; s < 5; ++s) {
            U4H b0, b1;
            b0.u = *(const uint4*)&r0p[kb + s * 16];
            b1.u = *(const uint4*)&r1p[kb + s * 16];
            acc[0][0] = __builtin_amdgcn_mfma_f32_16x16x32_f16(pa[s][0], b0.h, acc[0][0], 0, 0, 0);
            acc[0][1] = __builtin_amdgcn_mfma_f32_16x16x32_f16(pa[s][0], b1.h, acc[0][1], 0, 0, 0);
            acc[1][0] = __builtin_amdgcn_mfma_f32_16x16x32_f16(pa[s][1], b0.h, acc[1][0], 0, 0, 0);
            acc[1][1] = __builtin_amdgcn_mfma_f32_16x16x32_f16(pa[s][1], b1.h, acc[1][1], 0, 0, 0);
        }
    }

    // ---- epilogue: transpose via LDS -> float4 full-line stores ----
    #pragma unroll
    for (int mt = 0; mt < 2; ++mt)
        #pragma unroll
        for (int nt = 0; nt < 2; ++nt)
            #pragma unroll
            for (int r = 0; r < 4; ++r) {
                const int o  = mrow * 32 + mt * 16 + quad * 4 + r;
                const int px = ncol * 32 + nt * 16 + l16;
                tr[o * 68 + px] = acc[mt][nt][r] + bias[o];
            }
    __syncthreads();
    {
        const int orow = tid >> 2, f0 = tid & 3;
        #pragma unroll
        for (int it = 0; it < 4; ++it) {
            const int f = f0 + it * 4;
            const float4 v = *(const float4*)&tr[orow * 68 + (f << 2)];
            *(float4*)&out[(((size_t)b * On + orow) * Hn + h) * Wn + (f << 2)] = v;
        }
    }
}

// ======================= proven R12 fused kernel (ws >= 328 KB) =======================
__global__ __launch_bounds__(BDIM, 4)
void dcn_mfma_kernel(const float* __restrict__ x,
                     const float* __restrict__ offs,
                     const float* __restrict__ mask,
                     const u16*   __restrict__ wh,
                     const float* __restrict__ bias,
                     float* __restrict__ out)
{
    __shared__ __align__(16) u32 smem[SM_DW];   // pband | ash0 | ash1
    u32* const pband = smem;

    const int tid = threadIdx.x;
    const int b   = blockIdx.x & 7;             // batch <-> XCD affinity
    const int h   = blockIdx.x >> 3;
    const int r0  = min(max(h - 5, 0), Hn - BANDH);

    const int s_px4 = tid & 15, s_pair = (tid >> 4) & 7;

    float4 bnda[3], bndb[3];
#define BLOAD(GCH) { \
        _Pragma("unroll") \
        for (int it = 0; it < 3; ++it) { \
            const int u = tid + it * BDIM; \
            if (u < BUNITS) { \
                const int row = u >> 7; \
                const float* bp = x + (((size_t)(b * Cn + (GCH) * CG + 2 * s_pair)) << 12) \
                                  + (r0 + row) * Wn + (s_px4 << 2); \
                bnda[it] = *(const float4*)bp; \
                bndb[it] = *(const float4*)(bp + 4096); \
            } \
        } }
#define BWRITE() { \
        _Pragma("unroll") \
        for (int it = 0; it < 3; ++it) { \
            const int u = tid + it * BDIM; \
            if (u < BUNITS) { \
                const int row = u >> 7; \
                u32* d = &pband[s_pair * XSTP + row * RST + 8 + (s_px4 << 2)]; \
                *(uint4*)d = make_uint4( \
                    pkh(bnda[it].x, bndb[it].x), pkh(bnda[it].y, bndb[it].y), \
                    pkh(bnda[it].z, bndb[it].z), pkh(bnda[it].w, bndb[it].w)); \
            } \
        } }

    BLOAD(0);

    uint4 mwp[2]; int2 mq[2]; int2 mi[2];
    #pragma unroll
    for (int it = 0; it < 2; ++it) {
        mwp[it] = make_uint4(0, 0, 0, 0);
        mq[it] = make_int2(r0 << 8, r0 << 8);
        mi[it] = make_int2(7, 7);
        const int e = tid + it * BDIM;
        if (e < ME) {
            const int t = e >> 6, px = e & 63;
            const int ty = t / 3, tx = t - ty * 3;
            const float oy = offs[((b * 18 + 2 * t    ) * Hn + h) * Wn + px];
            const float ox = offs[((b * 18 + 2 * t + 1) * Hn + h) * Wn + px];
            const float m  = mask[((b * KK + t) * Hn + h) * Wn + px];
            const float py = (float)(h - PAD + ty) + oy;
            const float qx = (float)(px - PAD + tx) + ox;
            const float fy = floorf(py), fx = floorf(qx);
            const float wy1 = py - fy, wx1 = qx - fx;
            const float wy0 = 1.f - wy1, wx0 = 1.f - wx1;
            const int y0 = (int)fy, x0 = (int)fx;
            const bool cx0 = (x0 >= 0) && (x0 < Wn);
            const bool cx1 = (x0 >= -1) && (x0 < Wn - 1);
            const float wr[2] = { wy0, wy1 };
            float wout[4]; int qout[2], iout[2];
            #pragma unroll
            for (int j = 0; j < 2; ++j) {
                const int yr = y0 + j;
                const bool rv = (yr >= 0) && (yr < Hn);
                wout[2 * j]     = (rv && cx0) ? wr[j] * wx0 * m : 0.f;
                wout[2 * j + 1] = (rv && cx1) ? wr[j] * wx1 * m : 0.f;
                int qv;
                if (!rv || (!cx0 && !cx1)) qv = r0 << 8;
                else                       qv = (yr << 8) | (x0 + 1);
                const bool inband = (qv >> 8) >= r0 && (qv >> 8) < r0 + BANDH;
                qout[j] = inband ? qv : ~qv;
                iout[j] = ((qv >> 8) - r0) * RST + (qv & 255) + 7;
            }
            mwp[it] = make_uint4(pkh(wout[0], wout[0]), pkh(wout[1], wout[1]),
                                 pkh(wout[2], wout[2]), pkh(wout[3], wout[3]));
            mq[it] = make_int2(qout[0], qout[1]);
            mi[it] = make_int2(iout[0], iout[1]);
        }
    }

    if (tid < 416) {
        const int pair = tid / 52, j = tid - pair * 52;
        const int off = (j < 8) ? j : RST * ((j - 8) >> 2) + 72 + ((j - 8) & 3);
        pband[pair * XSTP + off] = 0;
    }
    #pragma unroll
    for (int it = 0; it < 2; ++it) {
        const int u = tid + it * BDIM;
        smem[PB_DW + (u >> 9) * ASH_DW + ((u & 511) >> 3) * AST + 72 + (u & 7)] = 0;
    }

    BWRITE();
    BLOAD(1);
    __syncthreads();

    const int wv = tid >> 6, ln = tid & 63, quad = ln >> 4, l16 = ln & 15;
    const int mrow = wv >> 1, ncol = wv & 1;
    const u16* wrow0 = wh + (size_t)(mrow * 32 + l16) * KTOT;
    const int npx0 = ncol * 32 + l16, npx1 = npx0 + 16;

    {
        const float* xg = x + (((size_t)(b * Cn)) << 12);
        do_sample(pband, smem + PB_DW, xg, mwp[0], mq[0], mi[0], tid);
        if (tid < 64)
            do_sample(pband, smem + PB_DW, xg, mwp[1], mq[1], mi[1], BDIM + tid);
    }
    __syncthreads();

    f32x4 acc[2][2];
    #pragma unroll
    for (int mt = 0; mt < 2; ++mt)
        #pragma unroll
        for (int nt = 0; nt < 2; ++nt) acc[mt][nt] = (f32x4){0.f, 0.f, 0.f, 0.f};

    f16x8 pa0[2], pa1[2];
#define APRE(GG) { const int kgp = (GG) * KG + quad * 8; \
        pa0[0] = *(const f16x8*)(wrow0 + kgp); \
        pa1[0] = *(const f16x8*)(wrow0 + 16 * KTOT + kgp); \
        pa0[1] = *(const f16x8*)(wrow0 + kgp + 32); \
        pa1[1] = *(const f16x8*)(wrow0 + 16 * KTOT + kgp + 32); }
    APRE(0);

#define MSTEP_PRE(S) { \
        const int kd = (S) * 16 + quad * 4; \
        U4H b0, b1; \
        b0.u = *(const uint4*)&ad[npx0 * AST + kd]; \
        b1.u = *(const uint4*)&ad[npx1 * AST + kd]; \
        acc[0][0] = __builtin_amdgcn_mfma_f32_16x16x32_f16(pa0[S], b0.h, acc[0][0], 0, 0, 0); \
        acc[0][1] = __builtin_amdgcn_mfma_f32_16x16x32_f16(pa0[S], b1.h, acc[0][1], 0, 0, 0); \
        acc[1][0] = __builtin_amdgcn_mfma_f32_16x16x32_f16(pa1[S], b0.h, acc[1][0], 0, 0, 0); \
        acc[1][1] = __builtin_amdgcn_mfma_f32_16x16x32_f16(pa1[S], b1.h, acc[1][1], 0, 0, 0); }

#define MSTEP_LD(S) { \
        const int kg = g * KG + (S) * 32 + quad * 8; \
        const f16x8 a0 = *(const f16x8*)(wrow0 + kg); \
        const f16x8 a1 = *(const f16x8*)(wrow0 + 16 * KTOT + kg); \
        const int kd = (S) * 16 + quad * 4; \
        U4H b0, b1; \
        b0.u = *(const uint4*)&ad[npx0 * AST + kd]; \
        b1.u = *(const uint4*)&ad[npx1 * AST + kd]; \
        acc[0][0] = __builtin_amdgcn_mfma_f32_16x16x32_f16(a0, b0.h, acc[0][0], 0, 0, 0); \
        acc[0][1] = __builtin_amdgcn_mfma_f32_16x16x32_f16(a0, b1.h, acc[0][1], 0, 0, 0); \
        acc[1][0] = __builtin_amdgcn_mfma_f32_16x16x32_f16(a1, b0.h, acc[1][0], 0, 0, 0); \
        acc[1][1] = __builtin_amdgcn_mfma_f32_16x16x32_f16(a1, b1.h, acc[1][1], 0, 0, 0); }

    for (int g = 0; g < NG; ++g) {
        const u32* ad = smem + PB_DW + (g & 1) * ASH_DW;
        u32* ashN     = smem + PB_DW + ((g + 1) & 1) * ASH_DW;
        if (g + 1 < NG) BWRITE();
        MSTEP_PRE(0);
        MSTEP_PRE(1);
        __syncthreads();
        if (g + 2 < NG) BLOAD(g + 2);
        if (g + 1 < NG) {
            const float* xg = x + (((size_t)(b * Cn + (g + 1) * CG)) << 12);
            do_sample(pband, ashN, xg, mwp[0], mq[0], mi[0], tid);
            if (tid < 64)
                do_sample(pband, ashN, xg, mwp[1], mq[1], mi[1], BDIM + tid);
        }
        MSTEP_LD(2);
        MSTEP_LD(3);
        MSTEP_LD(4);
        if (g + 1 < NG) APRE(g + 1);
        __syncthreads();
    }

    float* tr = (float*)smem;
    #pragma unroll
    for (int mt = 0; mt < 2; ++mt)
        #pragma unroll
        for (int nt = 0; nt < 2; ++nt)
            #pragma unroll
            for (int r = 0; r < 4; ++r) {
                const int o  = mrow * 32 + mt * 16 + quad * 4 + r;
                const int px = ncol * 32 + nt * 16 + l16;
                tr[o * 68 + px] = acc[mt][nt][r] + bias[o];
            }
    __syncthreads();
    {
        const int orow = tid >> 2, f0 = tid & 3;
        #pragma unroll
        for (int it = 0; it < 4; ++it) {
            const int f = f0 + it * 4;
            const float4 v = *(const float4*)&tr[orow * 68 + (f << 2)];
            *(float4*)&out[(((size_t)b * On + orow) * Hn + h) * Wn + (f << 2)] = v;
        }
    }
#undef BLOAD
#undef BWRITE
#undef APRE
#undef MSTEP_PRE
#undef MSTEP_LD
}

// ================= fallback: proven R2 fp32 kernel (no d_ws) =================
constexpr int FBD = 256;
constexpr int FB_PXB = 32, FB_CCH = 4, FB_NCT = FB_CCH * KK, FB_MW = KK * FB_PXB;

#define FMA4(A, S, W)                          \
    A.x = fmaf((S).x, (W), A.x);               \
    A.y = fmaf((S).y, (W), A.y);               \
    A.z = fmaf((S).z, (W), A.z);               \
    A.w = fmaf((S).w, (W), A.w);

__global__ __launch_bounds__(FBD, 4)
void dcn_fb_kernel(const float* __restrict__ x,
                   const float* __restrict__ offs,
                   const float* __restrict__ mask,
                   const float* __restrict__ weight,
                   const float* __restrict__ bias,
                   float* __restrict__ out)
{
    __shared__ float wmeta[4 * FB_MW];
    __shared__ int   imeta[4 * FB_MW];
    __shared__ float ssh[FB_NCT * FB_PXB];
    __shared__ float wsh[FB_NCT * On];

    const int tid    = threadIdx.x;
    const int b      = blockIdx.x & 7;
    const int rem    = blockIdx.x >> 3;
    const int h      = rem >> 1;
    const int pxbase = (rem & 1) * FB_PXB;

    for (int e = tid; e < FB_MW; e += FBD) {
        const int t  = e >> 5;
        const int px = e & 31;
        const int pg = pxbase + px;
        const int ty = t / 3, tx = t - ty * 3;
        const float oy = offs[((b * 18 + 2 * t    ) * Hn + h) * Wn + pg];
        const float ox = offs[((b * 18 + 2 * t + 1) * Hn + h) * Wn + pg];
        const float m  = mask[((b * KK + t) * Hn + h) * Wn + pg];
        const float py = (float)(h - PAD + ty) + oy;
        const float qx = (float)(pg - PAD + tx) + ox;
        const float y0 = floorf(py), x0 = floorf(qx);
        const float wy1 = py - y0, wx1 = qx - x0;
        const float wy0 = 1.f - wy1, wx0 = 1.f - wx1;
        const float cw[4] = { wy0 * wx0, wy0 * wx1, wy1 * wx0, wy1 * wx1 };
        #pragma unroll
        for (int k = 0; k < 4; ++k) {
            const float yk = y0 + (float)(k >> 1);
            const float xk = x0 + (float)(k & 1);
            const bool valid = (yk >= 0.f) && (yk <= (float)(Hn - 1)) &&
                               (xk >= 0.f) && (xk <= (float)(Wn - 1));
            const int yc = (int)fminf(fmaxf(yk, 0.f), (float)(Hn - 1));
            const int xc = (int)fminf(fmaxf(xk, 0.f), (float)(Wn - 1));
            wmeta[k * FB_MW + e] = valid ? cw[k] * m : 0.f;
            imeta[k * FB_MW + e] = yc * Wn + xc;
        }
    }
    __syncthreads();

    const int px0 = (tid & 7) << 2;
    const int oo  = (tid >> 3) << 2;

    float4 acc[4];
    #pragma unroll
    for (int j = 0; j < 4; ++j) acc[j] = make_float4(0.f, 0.f, 0.f, 0.f);

    for (int cb = 0; cb < Cn / FB_CCH; ++cb) {
        #pragma unroll
        for (int it = 0; it < (FB_NCT * On) / FBD; ++it) {
            const int e = tid + it * FBD;
            const int r = e >> 7;
            const int o = e & 127;
            wsh[r * On + o] = weight[o * (Cn * KK) + cb * FB_NCT + r];
        }
        for (int e = tid; e < FB_NCT * FB_PXB; e += FBD) {
            const int px = e & 31;
            const int ct = e >> 5;
            const int c  = ct / 9;
            const int mb = (ct - c * 9) * FB_PXB + px;
            const float* xp = x + (((b * Cn) + cb * FB_CCH + c) << 12);
            float v =  wmeta[mb]              * xp[imeta[mb]];
            v = fmaf(wmeta[FB_MW     + mb], xp[imeta[FB_MW     + mb]], v);
            v = fmaf(wmeta[2 * FB_MW + mb], xp[imeta[2 * FB_MW + mb]], v);
            v = fmaf(wmeta[3 * FB_MW + mb], xp[imeta[3 * FB_MW + mb]], v);
            ssh[ct * FB_PXB + px] = v;
        }
        __syncthreads();

        #pragma unroll 6
        for (int ct = 0; ct < FB_NCT; ++ct) {
            const float4 sv = *(const float4*)&ssh[ct * FB_PXB + px0];
            const float4 wa = *(const float4*)&wsh[ct * On + oo];
            FMA4(acc[0], sv, wa.x);
            FMA4(acc[1], sv, wa.y);
            FMA4(acc[2], sv, wa.z);
            FMA4(acc[3], sv, wa.w);
        }
        __syncthreads();
    }

    #pragma unroll
    for (int j = 0; j < 4; ++j) {
        const float bv = bias[oo + j];
        float4 r = acc[j];
        r.x += bv; r.y += bv; r.z += bv; r.w += bv;
        *(float4*)&out[((b * On + oo + j) * Hn + h) * Wn + pxbase + px0] = r;
    }
}

extern "C" void kernel_launch(void* const* d_in, const int* in_sizes, int n_in,
                              void* d_out, int out_size, void* d_ws, size_t ws_size,
                              hipStream_t stream) {
    const float* x      = (const float*)d_in[0];
    const float* offs   = (const float*)d_in[1];
    const float* mask   = (const float*)d_in[2];
    const float* weight = (const float*)d_in[3];
    const float* bias   = (const float*)d_in[4];
    float* out = (float*)d_out;

    const size_t need_fused = WH_BYTES;                 // 327,680 B
    const size_t need_split = S_BYTES + WH_BYTES;       // 84,213,760 B
    if (d_ws != nullptr && ws_size >= need_split) {
        u32* S32 = (u32*)d_ws;
        u16* wh  = (u16*)((char*)d_ws + S_BYTES);
        wprep_kernel<<<dim3(On), dim3(256), 0, stream>>>(weight, wh);
        dcn_im2col<<<dim3(2 * Bn * Hn), dim3(BDIM), 0, stream>>>(x, offs, mask, S32);
        dcn_gemm<<<dim3(Bn * Hn), dim3(BDIM), 0, stream>>>(S32, wh, bias, out);
    } else if (d_ws != nullptr && ws_size >= need_fused) {
        u16* wh = (u16*)d_ws;
        wprep_kernel<<<dim3(On), dim3(256), 0, stream>>>(weight, wh);
        dcn_mfma_kernel<<<dim3(Bn * Hn), dim3(BDIM), 0, stream>>>(
            x, offs, mask, wh, bias, out);
    } else {
        dcn_fb_kernel<<<dim3(Bn * Hn * 2), dim3(FBD), 0, stream>>>(
            x, offs, mask, weight, bias, out);
    }
}

// Round 7
// 179.723 us; speedup vs baseline: 1.0473x; 1.0473x over previous
//
#include <hip/hip_runtime.h>
#include <math.h>

// DCN v2: B=8, C=128, O=128, H=W=64, k=3, dil=1, dg=1, stride=1, pad=1.
// R15 = R14 resubmitted verbatim (R14 bench died to container-acquisition
// infra failure before running; source re-audited: S indexing in-bounds,
// k' mapping consistent, S fully covered, VGPR caps fit).
// R14: split path with coalesced S on BOTH sides (R13 post-mortem: gemm was
// latency-bound on 16B-at-2560B-stride scattered S reads; im2col writes same).
//   S layout: [b][h][ph][gc][gl*9+t][px32][16ch f16]  (75.5 MB, no padding)
//   - im2col: per-wave element writes = 64 lanes x 32B stride-32B = dense 2KB.
//   - gemm: per 288-k' chunk (2 granules = 9 MFMA K-steps exactly) stream a
//     CONTIGUOUS 18,432B slab -> regs -> LDS [px][148] (148%32==84%32: proven
//     conflict-free b128 pattern), double-buffered, 1 barrier/chunk, next
//     chunk's loads issued under current MFMA. A from L2-resident wh2.
//   - grid 1024 each, LDS 37.9KB, launch_bounds(512,6) -> 3-4 blocks/CU.
// Fallbacks kept: R12 fused (ws >= 328KB), fp32 (no ws).
constexpr int Bn = 8, Cn = 128, On = 128, Hn = 64, Wn = 64;
constexpr int KK = 9, PAD = 1;
constexpr int BDIM = 512;                 // 8 waves
constexpr int PXB  = 64;                  // full row per im2col block
constexpr int CG = 16, NG = Cn / CG;      // 8 channel granules
constexpr int KG = 160, KTOT = NG * KG;   // fused-path k layout (padded)
constexpr int BANDH = 11;                 // band rows (h-5 .. h+5)
constexpr int RST  = 68;                  // pband row stride (dwords)
constexpr int XSTP = 756;                 // pband pair stride (dwords)
constexpr int AST  = 84;                  // fused ash px stride (dwords)
constexpr int ME   = KK * PXB;            // 576 sampling elements
constexpr int PB_DW  = 8 * XSTP;          // 6048
constexpr int ASH_DW = PXB * AST;         // 5376
constexpr int SM_DW  = PB_DW + 2 * ASH_DW;// fused LDS (67,200 B)
constexpr int BUNITS = BANDH * 128;       // 1408 band load/write units

// ---- split-path layout ----
constexpr int KT2   = 1152;               // k' total, no pad
constexpr int AST2  = 148;                // gemm LDS px stride (dw), 16B-aligned
constexpr int CH_DW = 4608;               // S chunk stride (dw) = 2*9*32*8
constexpr int BUF_DW = 32 * AST2;         // 4736 dw per LDS buffer
constexpr size_t SBH_DW   = 36864;        // S dwords per (b,h)
constexpr size_t S2_BYTES = (size_t)Bn * Hn * SBH_DW * 4;   // 75,497,472
constexpr size_t WH2_BYTES = (size_t)On * KT2 * 2;          // 294,912
constexpr size_t WH_BYTES  = (size_t)On * KTOT * 2;         // 327,680 (fused)

typedef __attribute__((ext_vector_type(2))) _Float16 h2;      // arithmetic
typedef __attribute__((ext_vector_type(8))) __fp16   f16x8;   // MFMA operand
typedef __attribute__((ext_vector_type(4))) float f32x4;
typedef unsigned short u16;
typedef unsigned int u32;

union UH  { u32 u; h2 h; };
union U4H { uint4 u; f16x8 h; };

__device__ __forceinline__ u32 pkh(float a, float b) {  // low16 = f16(a), RTZ
    union { decltype(__builtin_amdgcn_cvt_pkrtz(0.f, 0.f)) p; u32 u; } t;
    t.p = __builtin_amdgcn_cvt_pkrtz(a, b);
    return t.u;
}
__device__ __forceinline__ h2 bch(u32 w) { UH t; t.u = w; return t.h; }
__device__ __forceinline__ u16 f2h(float f) {           // RNE f32->f16
    union { _Float16 h; u16 u; } v; v.h = (_Float16)f; return v.u;
}

// ---- fused-path weight prep: [O][KTOT=1280 padded] ----
__global__ void wprep_kernel(const float* __restrict__ w, u16* __restrict__ wh) {
    __shared__ u32 tmpw[KTOT / 2];
    u16* tmp = (u16*)tmpw;
    const int tid = threadIdx.x, o = blockIdx.x;
    if (tid < 64)
        tmpw[(tid >> 3) * 80 + 72 + (tid & 7)] = 0;
    for (int k = tid; k < Cn * KK; k += 256) {
        const int c = k / 9, t = k - 9 * c;
        tmp[(c >> 4) * KG + t * 16 + (c & 15)] = f2h(w[o * (Cn * KK) + k]);
    }
    __syncthreads();
    u32* dst = (u32*)(wh + (size_t)o * KTOT);
    for (int e = tid; e < KTOT / 2; e += 256) dst[e] = tmpw[e];
}

// ---- split-path weight prep: [O][KT2=1152], k' = (g*9+t)*16 + cl ----
__global__ void wprep2_kernel(const float* __restrict__ w, u16* __restrict__ wh2) {
    __shared__ u16 tmp[KT2];
    const int tid = threadIdx.x, o = blockIdx.x;
    for (int k = tid; k < KT2; k += 256) {
        const int c = k / 9, t = k - 9 * c;
        tmp[((c >> 4) * 9 + t) * 16 + (c & 15)] = f2h(w[o * KT2 + k]);
    }
    __syncthreads();
    u32* dst = (u32*)(wh2 + (size_t)o * KT2);
    for (int e = tid; e < KT2 / 2; e += 256) dst[e] = ((u32*)tmp)[e];
}

// ---- shared sampling core: gather 16 channels for one (tap,px) element ----
__device__ __forceinline__ void sample_core(const u32* __restrict__ pband,
                                            const float* __restrict__ xg,
                                            const uint4 wp, const int2 q,
                                            const int2 ix, u32* avp)
{
    if (!__any((q.x | q.y) < 0)) {           // all corners of wave in band
        const u32* p0 = pband + ix.x;
        const u32* p1 = pband + ix.y;
        const h2 w0 = bch(wp.x), w1 = bch(wp.y), w2 = bch(wp.z), w3 = bch(wp.w);
        #pragma unroll
        for (int c2 = 0; c2 < 8; ++c2) {
            const h2 vt0 = bch(p0[c2 * XSTP]), vt1 = bch(p0[c2 * XSTP + 1]);
            const h2 vb0 = bch(p1[c2 * XSTP]), vb1 = bch(p1[c2 * XSTP + 1]);
            const h2 r = w0 * vt0 + w1 * vt1 + w2 * vb0 + w3 * vb1;
            UH o; o.h = r; avp[c2] = o.u;
        }
    } else {                                  // rare: clamped global reads
        const float fw0 = (float)bch(wp.x)[0], fw1 = (float)bch(wp.y)[0];
        const float fw2 = (float)bch(wp.z)[0], fw3 = (float)bch(wp.w)[0];
        const int qx = q.x < 0 ? ~q.x : q.x;
        const int qy = q.y < 0 ? ~q.y : q.y;
        const int yrx = qx >> 8, yry = qy >> 8;
        const int xx = (qx & 255) - 1, xy = (qy & 255) - 1;
        const int ax0 = max(xx, 0), ax1 = min(xx + 1, Wn - 1);
        const int ay0 = max(xy, 0), ay1 = min(xy + 1, Wn - 1);
        #pragma unroll
        for (int c2 = 0; c2 < 8; ++c2) {
            float v2[2];
            #pragma unroll
            for (int sb = 0; sb < 2; ++sb) {
                const float* gc = xg + ((2 * c2 + sb) << 12);
                const float t0 = gc[yrx * Wn + ax0], t1 = gc[yrx * Wn + ax1];
                const float b0 = gc[yry * Wn + ay0], b1 = gc[yry * Wn + ay1];
                v2[sb] = fmaf(fw0, t0, fmaf(fw1, t1, fmaf(fw2, b0, fw3 * b1)));
            }
            avp[c2] = pkh(v2[0], v2[1]);
        }
    }
}

// fused-path variant: write to LDS ash
__device__ __forceinline__ void do_sample(const u32* __restrict__ pband,
                                          u32* __restrict__ ashW,
                                          const float* __restrict__ xg,
                                          const uint4 wp, const int2 q,
                                          const int2 ix, const int e)
{
    const int t = e >> 6, px = e & 63;
    u32 avp[8];
    sample_core(pband, xg, wp, q, ix, avp);
    u32* d = ashW + px * AST + t * 8;
    *(uint4*)&d[0] = make_uint4(avp[0], avp[1], avp[2], avp[3]);
    *(uint4*)&d[4] = make_uint4(avp[4], avp[5], avp[6], avp[7]);
}

// split-path variant: coalesced write to S. SgBH = S base for this (b,h).
// S dw = ph*18432 + gc*4608 + (gl*9+t)*256 + px5*8
__device__ __forceinline__ void do_sample_g(const u32* __restrict__ pband,
                                            u32* __restrict__ SgBH,
                                            const float* __restrict__ xg,
                                            const uint4 wp, const int2 q,
                                            const int2 ix, const int e,
                                            const int g)
{
    const int t = e >> 6, px = e & 63;
    u32 avp[8];
    sample_core(pband, xg, wp, q, ix, avp);
    u32* d = SgBH + (px >> 5) * 18432 + (g >> 1) * CH_DW
           + (((g & 1) * 9 + t) << 8) + ((px & 31) << 3);
    *(uint4*)&d[0] = make_uint4(avp[0], avp[1], avp[2], avp[3]);
    *(uint4*)&d[4] = make_uint4(avp[4], avp[5], avp[6], avp[7]);
}

// ======================= split kernel 1: im2col =======================
// grid 1024: b = bid&7, h = (bid>>3)&63, gset = bid>>9 (granules gset*4..+3)
__global__ __launch_bounds__(BDIM, 6)
void dcn_im2col(const float* __restrict__ x,
                const float* __restrict__ offs,
                const float* __restrict__ mask,
                u32* __restrict__ S32)
{
    __shared__ __align__(16) u32 pband[PB_DW];   // 24,192 B

    const int tid  = threadIdx.x;
    const int b    = blockIdx.x & 7;             // batch <-> XCD affinity
    const int h    = (blockIdx.x >> 3) & 63;
    const int g0   = (blockIdx.x >> 9) * 4;
    const int r0   = min(max(h - 5, 0), Hn - BANDH);
    const int s_px4 = tid & 15, s_pair = (tid >> 4) & 7;
    u32* const SgBH = S32 + (size_t)(b * 64 + h) * SBH_DW;

    float4 bnda[3], bndb[3];
#define BLOAD(GCH) { \
        _Pragma("unroll") \
        for (int it = 0; it < 3; ++it) { \
            const int u = tid + it * BDIM; \
            if (u < BUNITS) { \
                const int row = u >> 7; \
                const float* bp = x + (((size_t)(b * Cn + (GCH) * CG + 2 * s_pair)) << 12) \
                                  + (r0 + row) * Wn + (s_px4 << 2); \
                bnda[it] = *(const float4*)bp; \
                bndb[it] = *(const float4*)(bp + 4096); \
            } \
        } }
#define BWRITE() { \
        _Pragma("unroll") \
        for (int it = 0; it < 3; ++it) { \
            const int u = tid + it * BDIM; \
            if (u < BUNITS) { \
                const int row = u >> 7; \
                u32* d = &pband[s_pair * XSTP + row * RST + 8 + (s_px4 << 2)]; \
                *(uint4*)d = make_uint4( \
                    pkh(bnda[it].x, bndb[it].x), pkh(bnda[it].y, bndb[it].y), \
                    pkh(bnda[it].z, bndb[it].z), pkh(bnda[it].w, bndb[it].w)); \
            } \
        } }

    BLOAD(g0);   // issue first band loads before meta (latency overlap)

    // ---- meta in registers (identical to fused kernel) ----
    uint4 mwp[2]; int2 mq[2]; int2 mi[2];
    #pragma unroll
    for (int it = 0; it < 2; ++it) {
        mwp[it] = make_uint4(0, 0, 0, 0);
        mq[it] = make_int2(r0 << 8, r0 << 8);
        mi[it] = make_int2(7, 7);
        const int e = tid + it * BDIM;
        if (e < ME) {
            const int t = e >> 6, px = e & 63;
            const int ty = t / 3, tx = t - ty * 3;
            const float oy = offs[((b * 18 + 2 * t    ) * Hn + h) * Wn + px];
            const float ox = offs[((b * 18 + 2 * t + 1) * Hn + h) * Wn + px];
            const float m  = mask[((b * KK + t) * Hn + h) * Wn + px];
            const float py = (float)(h - PAD + ty) + oy;
            const float qx = (float)(px - PAD + tx) + ox;
            const float fy = floorf(py), fx = floorf(qx);
            const float wy1 = py - fy, wx1 = qx - fx;
            const float wy0 = 1.f - wy1, wx0 = 1.f - wx1;
            const int y0 = (int)fy, x0 = (int)fx;
            const bool cx0 = (x0 >= 0) && (x0 < Wn);
            const bool cx1 = (x0 >= -1) && (x0 < Wn - 1);
            const float wr[2] = { wy0, wy1 };
            float wout[4]; int qout[2], iout[2];
            #pragma unroll
            for (int j = 0; j < 2; ++j) {
                const int yr = y0 + j;
                const bool rv = (yr >= 0) && (yr < Hn);
                wout[2 * j]     = (rv && cx0) ? wr[j] * wx0 * m : 0.f;
                wout[2 * j + 1] = (rv && cx1) ? wr[j] * wx1 * m : 0.f;
                int qv;
                if (!rv || (!cx0 && !cx1)) qv = r0 << 8;   // junk: w=0, reads pad
                else                       qv = (yr << 8) | (x0 + 1);
                const bool inband = (qv >> 8) >= r0 && (qv >> 8) < r0 + BANDH;
                qout[j] = inband ? qv : ~qv;
                iout[j] = ((qv >> 8) - r0) * RST + (qv & 255) + 7;
            }
            mwp[it] = make_uint4(pkh(wout[0], wout[0]), pkh(wout[1], wout[1]),
                                 pkh(wout[2], wout[2]), pkh(wout[3], wout[3]));
            mq[it] = make_int2(qout[0], qout[1]);
            mi[it] = make_int2(iout[0], iout[1]);
        }
    }

    // ---- zero pband never-written gaps (NaN guard) ----
    if (tid < 416) {     // per pair: dwords 0..7 and 68r+72..75 (r=0..10)
        const int pair = tid / 52, j = tid - pair * 52;
        const int off = (j < 8) ? j : RST * ((j - 8) >> 2) + 72 + ((j - 8) & 3);
        pband[pair * XSTP + off] = 0;
    }

    BWRITE();           // band g0 -> pband
    BLOAD(g0 + 1);      // issue next band loads
    __syncthreads();

    const float* xb = x + (((size_t)(b * Cn)) << 12);
    for (int gg = 0; gg < 4; ++gg) {
        const int g = g0 + gg;
        const float* xg = xb + (((size_t)(g * CG)) << 12);
        do_sample_g(pband, SgBH, xg, mwp[0], mq[0], mi[0], tid, g);
        if (tid < 64)
            do_sample_g(pband, SgBH, xg, mwp[1], mq[1], mi[1], BDIM + tid, g);
        if (gg < 3) {
            __syncthreads();                 // pband reads done
            BWRITE();                        // band (g+1)
            if (gg < 2) BLOAD(g0 + gg + 2);  // issue band (g+2)
            __syncthreads();                 // pband ready
        }
    }
#undef BLOAD
#undef BWRITE
}

// ======================= split kernel 2: tiled GEMM =======================
// grid 1024: b = bid&7, h = (bid>>3)&63, ph = bid>>9. C tile 128o x 32px.
__global__ __launch_bounds__(BDIM, 6)
void dcn_gemm(const u32* __restrict__ S32,
              const u16* __restrict__ wh2,
              const float* __restrict__ bias,
              float* __restrict__ out)
{
    __shared__ __align__(16) u32 gsm[2 * BUF_DW];   // 37,888 B

    const int tid = threadIdx.x;
    const int b   = blockIdx.x & 7;
    const int h   = (blockIdx.x >> 3) & 63;
    const int ph  = blockIdx.x >> 9;

    const int wv = tid >> 6, ln = tid & 63, quad = ln >> 4, l16 = ln & 15;
    const int mrow = wv >> 1, ncol = wv & 1;        // 4x2 wave tiling
    const int npx = ncol * 16 + l16;                // 0..31
    const u16* wA = wh2 + (size_t)(mrow * 32 + l16) * KT2;
    const u32* Sbh = S32 + (size_t)(b * 64 + h) * SBH_DW + (size_t)ph * 18432;

    uint4 ld0, ld1, ld2;
#define LOADC(GC) { const u32* Sc = Sbh + (GC) * CH_DW; \
        ld0 = *(const uint4*)(Sc + (tid << 2)); \
        ld1 = *(const uint4*)(Sc + ((tid + 512) << 2)); \
        if (tid < 128) ld2 = *(const uint4*)(Sc + ((tid + 1024) << 2)); }
#define WRITEC(BUF) { \
        { const int q = tid >> 6, rem = tid & 63; \
          *(uint4*)&(BUF)[(rem >> 1) * AST2 + q * 8 + (rem & 1) * 4] = ld0; } \
        { const int u4 = tid + 512; const int q = u4 >> 6, rem = u4 & 63; \
          *(uint4*)&(BUF)[(rem >> 1) * AST2 + q * 8 + (rem & 1) * 4] = ld1; } \
        if (tid < 128) { const int u4 = tid + 1024; const int q = u4 >> 6, rem = u4 & 63; \
          *(uint4*)&(BUF)[(rem >> 1) * AST2 + q * 8 + (rem & 1) * 4] = ld2; } }

    f32x4 acc[2];
    acc[0] = (f32x4){0.f, 0.f, 0.f, 0.f};
    acc[1] = (f32x4){0.f, 0.f, 0.f, 0.f};

    LOADC(0);
    WRITEC(gsm);            // buf0
    LOADC(1);
    __syncthreads();

#define GSTEP(S) { \
        const f16x8 a0 = *(const f16x8*)(wA + kb + 32 * (S) + quad * 8); \
        const f16x8 a1 = *(const f16x8*)(wA + 16 * KT2 + kb + 32 * (S) + quad * 8); \
        U4H bb; bb.u = *(const uint4*)&bufc[npx * AST2 + (S) * 16 + quad * 4]; \
        acc[0] = __builtin_amdgcn_mfma_f32_16x16x32_f16(a0, bb.h, acc[0], 0, 0, 0); \
        acc[1] = __builtin_amdgcn_mfma_f32_16x16x32_f16(a1, bb.h, acc[1], 0, 0, 0); }

    #pragma unroll 1
    for (int gc = 0; gc < 4; ++gc) {
        const u32* bufc = gsm + (gc & 1) * BUF_DW;
        const int kb = gc * 288;
        GSTEP(0); GSTEP(1); GSTEP(2); GSTEP(3); GSTEP(4);
        GSTEP(5); GSTEP(6); GSTEP(7); GSTEP(8);
        if (gc < 3) {
            u32* bufn = gsm + ((gc + 1) & 1) * BUF_DW;
            WRITEC(bufn);                 // waits on ld regs (issued last iter)
            if (gc < 2) LOADC(gc + 2);    // refill under next chunk's MFMA
        }
        __syncthreads();
    }

    // ---- epilogue: transpose via LDS (stride 36) -> 64B-coalesced stores ----
    float* tr = (float*)gsm;              // 128 o x 32 px, 18,432 B (fits buf0)
    #pragma unroll
    for (int mt = 0; mt < 2; ++mt)
        #pragma unroll
        for (int r = 0; r < 4; ++r) {
            const int o = mrow * 32 + mt * 16 + quad * 4 + r;
            tr[o * 36 + npx] = acc[mt][r] + bias[o];
        }
    __syncthreads();
    {
        const int orow = tid >> 2, c0 = tid & 3;
        float* ob = out + ((size_t)(b * On + orow) << 12) + h * 64 + ph * 32;
        #pragma unroll
        for (int it = 0; it < 2; ++it) {
            const int f = c0 + it * 4;
            *(float4*)&ob[f << 2] = *(const float4*)&tr[orow * 36 + (f << 2)];
        }
    }
#undef LOADC
#undef WRITEC
#undef GSTEP
}

// ======================= proven R12 fused kernel (ws >= 328 KB) =======================
__global__ __launch_bounds__(BDIM, 4)
void dcn_mfma_kernel(const float* __restrict__ x,
                     const float* __restrict__ offs,
                     const float* __restrict__ mask,
                     const u16*   __restrict__ wh,
                     const float* __restrict__ bias,
                     float* __restrict__ out)
{
    __shared__ __align__(16) u32 smem[SM_DW];   // pband | ash0 | ash1
    u32* const pband = smem;

    const int tid = threadIdx.x;
    const int b   = blockIdx.x & 7;             // batch <-> XCD affinity
    const int h   = blockIdx.x >> 3;
    const int r0  = min(max(h - 5, 0), Hn - BANDH);

    const int s_px4 = tid & 15, s_pair = (tid >> 4) & 7;

    float4 bnda[3], bndb[3];
#define BLOAD(GCH) { \
        _Pragma("unroll") \
        for (int it = 0; it < 3; ++it) { \
            const int u = tid + it * BDIM; \
            if (u < BUNITS) { \
                const int row = u >> 7; \
                const float* bp = x + (((size_t)(b * Cn + (GCH) * CG + 2 * s_pair)) << 12) \
                                  + (r0 + row) * Wn + (s_px4 << 2); \
                bnda[it] = *(const float4*)bp; \
                bndb[it] = *(const float4*)(bp + 4096); \
            } \
        } }
#define BWRITE() { \
        _Pragma("unroll") \
        for (int it = 0; it < 3; ++it) { \
            const int u = tid + it * BDIM; \
            if (u < BUNITS) { \
                const int row = u >> 7; \
                u32* d = &pband[s_pair * XSTP + row * RST + 8 + (s_px4 << 2)]; \
                *(uint4*)d = make_uint4( \
                    pkh(bnda[it].x, bndb[it].x), pkh(bnda[it].y, bndb[it].y), \
                    pkh(bnda[it].z, bndb[it].z), pkh(bnda[it].w, bndb[it].w)); \
            } \
        } }

    BLOAD(0);

    uint4 mwp[2]; int2 mq[2]; int2 mi[2];
    #pragma unroll
    for (int it = 0; it < 2; ++it) {
        mwp[it] = make_uint4(0, 0, 0, 0);
        mq[it] = make_int2(r0 << 8, r0 << 8);
        mi[it] = make_int2(7, 7);
        const int e = tid + it * BDIM;
        if (e < ME) {
            const int t = e >> 6, px = e & 63;
            const int ty = t / 3, tx = t - ty * 3;
            const float oy = offs[((b * 18 + 2 * t    ) * Hn + h) * Wn + px];
            const float ox = offs[((b * 18 + 2 * t + 1) * Hn + h) * Wn + px];
            const float m  = mask[((b * KK + t) * Hn + h) * Wn + px];
            const float py = (float)(h - PAD + ty) + oy;
            const float qx = (float)(px - PAD + tx) + ox;
            const float fy = floorf(py), fx = floorf(qx);
            const float wy1 = py - fy, wx1 = qx - fx;
            const float wy0 = 1.f - wy1, wx0 = 1.f - wx1;
            const int y0 = (int)fy, x0 = (int)fx;
            const bool cx0 = (x0 >= 0) && (x0 < Wn);
            const bool cx1 = (x0 >= -1) && (x0 < Wn - 1);
            const float wr[2] = { wy0, wy1 };
            float wout[4]; int qout[2], iout[2];
            #pragma unroll
            for (int j = 0; j < 2; ++j) {
                const int yr = y0 + j;
                const bool rv = (yr >= 0) && (yr < Hn);
                wout[2 * j]     = (rv && cx0) ? wr[j] * wx0 * m : 0.f;
                wout[2 * j + 1] = (rv && cx1) ? wr[j] * wx1 * m : 0.f;
                int qv;
                if (!rv || (!cx0 && !cx1)) qv = r0 << 8;
                else                       qv = (yr << 8) | (x0 + 1);
                const bool inband = (qv >> 8) >= r0 && (qv >> 8) < r0 + BANDH;
                qout[j] = inband ? qv : ~qv;
                iout[j] = ((qv >> 8) - r0) * RST + (qv & 255) + 7;
            }
            mwp[it] = make_uint4(pkh(wout[0], wout[0]), pkh(wout[1], wout[1]),
                                 pkh(wout[2], wout[2]), pkh(wout[3], wout[3]));
            mq[it] = make_int2(qout[0], qout[1]);
            mi[it] = make_int2(iout[0], iout[1]);
        }
    }

    if (tid < 416) {
        const int pair = tid / 52, j = tid - pair * 52;
        const int off = (j < 8) ? j : RST * ((j - 8) >> 2) + 72 + ((j - 8) & 3);
        pband[pair * XSTP + off] = 0;
    }
    #pragma unroll
    for (int it = 0; it < 2; ++it) {
        const int u = tid + it * BDIM;
        smem[PB_DW + (u >> 9) * ASH_DW + ((u & 511) >> 3) * AST + 72 + (u & 7)] = 0;
    }

    BWRITE();
    BLOAD(1);
    __syncthreads();

    const int wv = tid >> 6, ln = tid & 63, quad = ln >> 4, l16 = ln & 15;
    const int mrow = wv >> 1, ncol = wv & 1;
    const u16* wrow0 = wh + (size_t)(mrow * 32 + l16) * KTOT;
    const int npx0 = ncol * 32 + l16, npx1 = npx0 + 16;

    {
        const float* xg = x + (((size_t)(b * Cn)) << 12);
        do_sample(pband, smem + PB_DW, xg, mwp[0], mq[0], mi[0], tid);
        if (tid < 64)
            do_sample(pband, smem + PB_DW, xg, mwp[1], mq[1], mi[1], BDIM + tid);
    }
    __syncthreads();

    f32x4 acc[2][2];
    #pragma unroll
    for (int mt = 0; mt < 2; ++mt)
        #pragma unroll
        for (int nt = 0; nt < 2; ++nt) acc[mt][nt] = (f32x4){0.f, 0.f, 0.f, 0.f};

    f16x8 pa0[2], pa1[2];
#define APRE(GG) { const int kgp = (GG) * KG + quad * 8; \
        pa0[0] = *(const f16x8*)(wrow0 + kgp); \
        pa1[0] = *(const f16x8*)(wrow0 + 16 * KTOT + kgp); \
        pa0[1] = *(const f16x8*)(wrow0 + kgp + 32); \
        pa1[1] = *(const f16x8*)(wrow0 + 16 * KTOT + kgp + 32); }
    APRE(0);

#define MSTEP_PRE(S) { \
        const int kd = (S) * 16 + quad * 4; \
        U4H b0, b1; \
        b0.u = *(const uint4*)&ad[npx0 * AST + kd]; \
        b1.u = *(const uint4*)&ad[npx1 * AST + kd]; \
        acc[0][0] = __builtin_amdgcn_mfma_f32_16x16x32_f16(pa0[S], b0.h, acc[0][0], 0, 0, 0); \
        acc[0][1] = __builtin_amdgcn_mfma_f32_16x16x32_f16(pa0[S], b1.h, acc[0][1], 0, 0, 0); \
        acc[1][0] = __builtin_amdgcn_mfma_f32_16x16x32_f16(pa1[S], b0.h, acc[1][0], 0, 0, 0); \
        acc[1][1] = __builtin_amdgcn_mfma_f32_16x16x32_f16(pa1[S], b1.h, acc[1][1], 0, 0, 0); }

#define MSTEP_LD(S) { \
        const int kg = g * KG + (S) * 32 + quad * 8; \
        const f16x8 a0 = *(const f16x8*)(wrow0 + kg); \
        const f16x8 a1 = *(const f16x8*)(wrow0 + 16 * KTOT + kg); \
        const int kd = (S) * 16 + quad * 4; \
        U4H b0, b1; \
        b0.u = *(const uint4*)&ad[npx0 * AST + kd]; \
        b1.u = *(const uint4*)&ad[npx1 * AST + kd]; \
        acc[0][0] = __builtin_amdgcn_mfma_f32_16x16x32_f16(a0, b0.h, acc[0][0], 0, 0, 0); \
        acc[0][1] = __builtin_amdgcn_mfma_f32_16x16x32_f16(a0, b1.h, acc[0][1], 0, 0, 0); \
        acc[1][0] = __builtin_amdgcn_mfma_f32_16x16x32_f16(a1, b0.h, acc[1][0], 0, 0, 0); \
        acc[1][1] = __builtin_amdgcn_mfma_f32_16x16x32_f16(a1, b1.h, acc[1][1], 0, 0, 0); }

    for (int g = 0; g < NG; ++g) {
        const u32* ad = smem + PB_DW + (g & 1) * ASH_DW;
        u32* ashN     = smem + PB_DW + ((g + 1) & 1) * ASH_DW;
        if (g + 1 < NG) BWRITE();
        MSTEP_PRE(0);
        MSTEP_PRE(1);
        __syncthreads();
        if (g + 2 < NG) BLOAD(g + 2);
        if (g + 1 < NG) {
            const float* xg = x + (((size_t)(b * Cn + (g + 1) * CG)) << 12);
            do_sample(pband, ashN, xg, mwp[0], mq[0], mi[0], tid);
            if (tid < 64)
                do_sample(pband, ashN, xg, mwp[1], mq[1], mi[1], BDIM + tid);
        }
        MSTEP_LD(2);
        MSTEP_LD(3);
        MSTEP_LD(4);
        if (g + 1 < NG) APRE(g + 1);
        __syncthreads();
    }

    float* tr = (float*)smem;
    #pragma unroll
    for (int mt = 0; mt < 2; ++mt)
        #pragma unroll
        for (int nt = 0; nt < 2; ++nt)
            #pragma unroll
            for (int r = 0; r < 4; ++r) {
                const int o  = mrow * 32 + mt * 16 + quad * 4 + r;
                const int px = ncol * 32 + nt * 16 + l16;
                tr[o * 68 + px] = acc[mt][nt][r] + bias[o];
            }
    __syncthreads();
    {
        const int orow = tid >> 2, f0 = tid & 3;
        #pragma unroll
        for (int it = 0; it < 4; ++it) {
            const int f = f0 + it * 4;
            const float4 v = *(const float4*)&tr[orow * 68 + (f << 2)];
            *(float4*)&out[(((size_t)b * On + orow) * Hn + h) * Wn + (f << 2)] = v;
        }
    }
#undef BLOAD
#undef BWRITE
#undef APRE
#undef MSTEP_PRE
#undef MSTEP_LD
}

// ================= fallback: proven R2 fp32 kernel (no d_ws) =================
constexpr int FBD = 256;
constexpr int FB_PXB = 32, FB_CCH = 4, FB_NCT = FB_CCH * KK, FB_MW = KK * FB_PXB;

#define FMA4(A, S, W)                          \
    A.x = fmaf((S).x, (W), A.x);               \
    A.y = fmaf((S).y, (W), A.y);               \
    A.z = fmaf((S).z, (W), A.z);               \
    A.w = fmaf((S).w, (W), A.w);

__global__ __launch_bounds__(FBD, 4)
void dcn_fb_kernel(const float* __restrict__ x,
                   const float* __restrict__ offs,
                   const float* __restrict__ mask,
                   const float* __restrict__ weight,
                   const float* __restrict__ bias,
                   float* __restrict__ out)
{
    __shared__ float wmeta[4 * FB_MW];
    __shared__ int   imeta[4 * FB_MW];
    __shared__ float ssh[FB_NCT * FB_PXB];
    __shared__ float wsh[FB_NCT * On];

    const int tid    = threadIdx.x;
    const int b      = blockIdx.x & 7;
    const int rem    = blockIdx.x >> 3;
    const int h      = rem >> 1;
    const int pxbase = (rem & 1) * FB_PXB;

    for (int e = tid; e < FB_MW; e += FBD) {
        const int t  = e >> 5;
        const int px = e & 31;
        const int pg = pxbase + px;
        const int ty = t / 3, tx = t - ty * 3;
        const float oy = offs[((b * 18 + 2 * t    ) * Hn + h) * Wn + pg];
        const float ox = offs[((b * 18 + 2 * t + 1) * Hn + h) * Wn + pg];
        const float m  = mask[((b * KK + t) * Hn + h) * Wn + pg];
        const float py = (float)(h - PAD + ty) + oy;
        const float qx = (float)(pg - PAD + tx) + ox;
        const float y0 = floorf(py), x0 = floorf(qx);
        const float wy1 = py - y0, wx1 = qx - x0;
        const float wy0 = 1.f - wy1, wx0 = 1.f - wx1;
        const float cw[4] = { wy0 * wx0, wy0 * wx1, wy1 * wx0, wy1 * wx1 };
        #pragma unroll
        for (int k = 0; k < 4; ++k) {
            const float yk = y0 + (float)(k >> 1);
            const float xk = x0 + (float)(k & 1);
            const bool valid = (yk >= 0.f) && (yk <= (float)(Hn - 1)) &&
                               (xk >= 0.f) && (xk <= (float)(Wn - 1));
            const int yc = (int)fminf(fmaxf(yk, 0.f), (float)(Hn - 1));
            const int xc = (int)fminf(fmaxf(xk, 0.f), (float)(Wn - 1));
            wmeta[k * FB_MW + e] = valid ? cw[k] * m : 0.f;
            imeta[k * FB_MW + e] = yc * Wn + xc;
        }
    }
    __syncthreads();

    const int px0 = (tid & 7) << 2;
    const int oo  = (tid >> 3) << 2;

    float4 acc[4];
    #pragma unroll
    for (int j = 0; j < 4; ++j) acc[j] = make_float4(0.f, 0.f, 0.f, 0.f);

    for (int cb = 0; cb < Cn / FB_CCH; ++cb) {
        #pragma unroll
        for (int it = 0; it < (FB_NCT * On) / FBD; ++it) {
            const int e = tid + it * FBD;
            const int r = e >> 7;
            const int o = e & 127;
            wsh[r * On + o] = weight[o * (Cn * KK) + cb * FB_NCT + r];
        }
        for (int e = tid; e < FB_NCT * FB_PXB; e += FBD) {
            const int px = e & 31;
            const int ct = e >> 5;
            const int c  = ct / 9;
            const int mb = (ct - c * 9) * FB_PXB + px;
            const float* xp = x + (((b * Cn) + cb * FB_CCH + c) << 12);
            float v =  wmeta[mb]              * xp[imeta[mb]];
            v = fmaf(wmeta[FB_MW     + mb], xp[imeta[FB_MW     + mb]], v);
            v = fmaf(wmeta[2 * FB_MW + mb], xp[imeta[2 * FB_MW + mb]], v);
            v = fmaf(wmeta[3 * FB_MW + mb], xp[imeta[3 * FB_MW + mb]], v);
            ssh[ct * FB_PXB + px] = v;
        }
        __syncthreads();

        #pragma unroll 6
        for (int ct = 0; ct < FB_NCT; ++ct) {
            const float4 sv = *(const float4*)&ssh[ct * FB_PXB + px0];
            const float4 wa = *(const float4*)&wsh[ct * On + oo];
            FMA4(acc[0], sv, wa.x);
            FMA4(acc[1], sv, wa.y);
            FMA4(acc[2], sv, wa.z);
            FMA4(acc[3], sv, wa.w);
        }
        __syncthreads();
    }

    #pragma unroll
    for (int j = 0; j < 4; ++j) {
        const float bv = bias[oo + j];
        float4 r = acc[j];
        r.x += bv; r.y += bv; r.z += bv; r.w += bv;
        *(float4*)&out[((b * On + oo + j) * Hn + h) * Wn + pxbase + px0] = r;
    }
}

extern "C" void kernel_launch(void* const* d_in, const int* in_sizes, int n_in,
                              void* d_out, int out_size, void* d_ws, size_t ws_size,
                              hipStream_t stream) {
    const float* x      = (const float*)d_in[0];
    const float* offs   = (const float*)d_in[1];
    const float* mask   = (const float*)d_in[2];
    const float* weight = (const float*)d_in[3];
    const float* bias   = (const float*)d_in[4];
    float* out = (float*)d_out;

    const size_t need_split = S2_BYTES + WH2_BYTES;     // 75,792,384 B
    if (d_ws != nullptr && ws_size >= need_split) {
        u32* S32 = (u32*)d_ws;
        u16* wh2 = (u16*)((char*)d_ws + S2_BYTES);
        wprep2_kernel<<<dim3(On), dim3(256), 0, stream>>>(weight, wh2);
        dcn_im2col<<<dim3(2 * Bn * Hn), dim3(BDIM), 0, stream>>>(x, offs, mask, S32);
        dcn_gemm<<<dim3(2 * Bn * Hn), dim3(BDIM), 0, stream>>>(S32, wh2, bias, out);
    } else if (d_ws != nullptr && ws_size >= WH_BYTES) {
        u16* wh = (u16*)d_ws;
        wprep_kernel<<<dim3(On), dim3(256), 0, stream>>>(weight, wh);
        dcn_mfma_kernel<<<dim3(Bn * Hn), dim3(BDIM), 0, stream>>>(
            x, offs, mask, wh, bias, out);
    } else {
        dcn_fb_kernel<<<dim3(Bn * Hn * 2), dim3(FBD), 0, stream>>>(
            x, offs, mask, weight, bias, out);
    }
}

// Round 9
// 170.513 us; speedup vs baseline: 1.1038x; 1.0540x over previous
//
#include <hip/hip_runtime.h>
#include <math.h>

// DCN v2: B=8, C=128, O=128, H=W=64, k=3, dil=1, dg=1, stride=1, pad=1.
// R17 = R16 with the NaN bug fixed: wprep3's weight-K-pad zeroing used
// "if (tid < 384)" in a 256-thread block -> granules 10..15 pads were
// uninitialized LDS garbage -> f16 Inf/NaN x 0 = NaN in MFMA. Now a strided
// loop covers all 384 pad entries.
// R16 design (occupancy restructure of proven R12 fused pipeline):
//   PXB=32, CG=8, grid 1024. pband 4 pairs x 756 = 12.1KB; ash 2 x 32x52 =
//   13.3KB -> LDS 25.4KB. VGPR forced <=64 (launch_bounds(512,8)): acc[2]
//   (16o x 32px per wave, single A-row -> A reuse x2), band regs 16, no
//   A-prefetch. => 4 blocks/CU, 32 waves resident (was 16).
//   K/granule = 72 real padded to 96 = 3 exact MFMA K-steps; ash stride 52
//   (=20 mod 32, proven 2-way-free b128). Sampling = 288 elems = 1/thread;
//   waves 5-7 skip sampling and enter MFMA early (role-split).
// Fallback: proven R2 fp32 kernel (no ws).
constexpr int Bn = 8, Cn = 128, On = 128, Hn = 64, Wn = 64;
constexpr int KK = 9, PAD = 1;
constexpr int BDIM = 512;                 // 8 waves
constexpr int BANDH = 11;                 // band rows (h-5 .. h+5)
constexpr int RST  = 68;                  // pband row stride (dwords)
constexpr int XSTP = 756;                 // pband pair stride (dwords)

// ---- geometry ----
constexpr int PXB3 = 32;                  // pixels per block (half row)
constexpr int CG3  = 8,  NG3 = 16;        // 8 channels per granule, 16 granules
constexpr int KG3  = 96;                  // padded K per granule (72 real)
constexpr int KT3  = NG3 * KG3;           // 1536
constexpr int AST3 = 52;                  // ash px stride (dw), 20 mod 32
constexpr int ME3  = KK * PXB3;           // 288 sampling elements
constexpr int PB3_DW  = 4 * XSTP;         // 3024
constexpr int ASH3_DW = PXB3 * AST3;      // 1664
constexpr int SM3_DW  = PB3_DW + 2 * ASH3_DW;   // 6352 dw = 25,408 B
constexpr int BU3  = BANDH * 64;          // 704 band units (4 pairs x 11 x 16)
constexpr size_t WH3_BYTES = (size_t)On * KT3 * 2;   // 393,216 B

typedef __attribute__((ext_vector_type(2))) _Float16 h2;      // arithmetic
typedef __attribute__((ext_vector_type(8))) __fp16   f16x8;   // MFMA operand
typedef __attribute__((ext_vector_type(4))) float f32x4;
typedef unsigned short u16;
typedef unsigned int u32;

union UH  { u32 u; h2 h; };
union U4H { uint4 u; f16x8 h; };

__device__ __forceinline__ u32 pkh(float a, float b) {  // low16 = f16(a), RTZ
    union { decltype(__builtin_amdgcn_cvt_pkrtz(0.f, 0.f)) p; u32 u; } t;
    t.p = __builtin_amdgcn_cvt_pkrtz(a, b);
    return t.u;
}
__device__ __forceinline__ h2 bch(u32 w) { UH t; t.u = w; return t.h; }
__device__ __forceinline__ u16 f2h(float f) {           // RNE f32->f16
    union { _Float16 h; u16 u; } v; v.h = (_Float16)f; return v.u;
}

// weight [O][C*9] fp32 -> wh3 [O][KT3=1536] f16, k' = g*96 + t*8 + cl
// (g = c>>3, cl = c&7); k' in [g*96+72, g*96+96) zero pad.
__global__ void wprep3_kernel(const float* __restrict__ w, u16* __restrict__ wh3) {
    __shared__ u16 tmp[KT3];
    const int tid = threadIdx.x, o = blockIdx.x;
    for (int e = tid; e < 384; e += 256) {   // zero pads: 16 granules x 24 (FIXED)
        const int g = e / 24, j = e - g * 24;
        tmp[g * 96 + 72 + j] = 0;
    }
    for (int k = tid; k < Cn * KK; k += 256) {
        const int c = k / 9, t = k - 9 * c;
        tmp[(c >> 3) * 96 + t * 8 + (c & 7)] = f2h(w[o * (Cn * KK) + k]);
    }
    __syncthreads();
    u32* dst = (u32*)(wh3 + (size_t)o * KT3);
    for (int e = tid; e < KT3 / 2; e += 256) dst[e] = ((u32*)tmp)[e];
}

// sampling of one (tap,px) element for one 8-channel granule.
__device__ __forceinline__ void sample3(const u32* __restrict__ pband,
                                        u32* __restrict__ ashW,
                                        const float* __restrict__ xg,
                                        const uint4 wp, const int2 q,
                                        const int2 ix, const int tid)
{
    const int t = tid >> 5, px = tid & 31;
    u32 avp[4];
    if (!__any((q.x | q.y) < 0)) {           // all active corners in band
        const u32* p0 = pband + ix.x;
        const u32* p1 = pband + ix.y;
        const h2 w0 = bch(wp.x), w1 = bch(wp.y), w2 = bch(wp.z), w3 = bch(wp.w);
        #pragma unroll
        for (int c2 = 0; c2 < 4; ++c2) {
            const h2 vt0 = bch(p0[c2 * XSTP]), vt1 = bch(p0[c2 * XSTP + 1]);
            const h2 vb0 = bch(p1[c2 * XSTP]), vb1 = bch(p1[c2 * XSTP + 1]);
            const h2 r = w0 * vt0 + w1 * vt1 + w2 * vb0 + w3 * vb1;
            UH o; o.h = r; avp[c2] = o.u;
        }
    } else {                                  // rare: clamped global reads
        const float fw0 = (float)bch(wp.x)[0], fw1 = (float)bch(wp.y)[0];
        const float fw2 = (float)bch(wp.z)[0], fw3 = (float)bch(wp.w)[0];
        const int qx = q.x < 0 ? ~q.x : q.x;
        const int qy = q.y < 0 ? ~q.y : q.y;
        const int yrx = qx >> 8, yry = qy >> 8;
        const int xx = (qx & 255) - 1, xy = (qy & 255) - 1;
        const int ax0 = max(xx, 0), ax1 = min(xx + 1, Wn - 1);
        const int ay0 = max(xy, 0), ay1 = min(xy + 1, Wn - 1);
        #pragma unroll
        for (int c2 = 0; c2 < 4; ++c2) {
            float v2[2];
            #pragma unroll
            for (int sb = 0; sb < 2; ++sb) {
                const float* gc = xg + ((2 * c2 + sb) << 12);
                const float t0 = gc[yrx * Wn + ax0], t1 = gc[yrx * Wn + ax1];
                const float b0 = gc[yry * Wn + ay0], b1 = gc[yry * Wn + ay1];
                v2[sb] = fmaf(fw0, t0, fmaf(fw1, t1, fmaf(fw2, b0, fw3 * b1)));
            }
            avp[c2] = pkh(v2[0], v2[1]);
        }
    }
    *(uint4*)(ashW + px * AST3 + t * 4) = make_uint4(avp[0], avp[1], avp[2], avp[3]);
}

__global__ __launch_bounds__(BDIM, 8)
void dcn_cg8_kernel(const float* __restrict__ x,
                    const float* __restrict__ offs,
                    const float* __restrict__ mask,
                    const u16*   __restrict__ wh3,
                    const float* __restrict__ bias,
                    float* __restrict__ out)
{
    __shared__ __align__(16) u32 smem[SM3_DW];   // pband | ash0 | ash1
    u32* const pband = smem;

    const int tid    = threadIdx.x;
    const int b      = blockIdx.x & 7;           // batch <-> XCD affinity
    const int h      = (blockIdx.x >> 3) & 63;
    const int pxbase = (blockIdx.x >> 9) * PXB3;
    const int r0     = min(max(h - 5, 0), Hn - BANDH);

    float4 bnda[2], bndb[2];
#define BLOAD3(GCH) { \
        _Pragma("unroll") \
        for (int it = 0; it < 2; ++it) { \
            const int u = tid + it * BDIM; \
            if (u < BU3) { \
                const int px4 = u & 15, pair = (u >> 4) & 3, row = u >> 6; \
                const float* bp = x + (((size_t)(b * Cn + (GCH) * CG3 + 2 * pair)) << 12) \
                                  + (r0 + row) * Wn + (px4 << 2); \
                bnda[it] = *(const float4*)bp; \
                bndb[it] = *(const float4*)(bp + 4096); \
            } \
        } }
#define BWRITE3() { \
        _Pragma("unroll") \
        for (int it = 0; it < 2; ++it) { \
            const int u = tid + it * BDIM; \
            if (u < BU3) { \
                const int px4 = u & 15, pair = (u >> 4) & 3, row = u >> 6; \
                u32* d = &pband[pair * XSTP + row * RST + 8 + (px4 << 2)]; \
                *(uint4*)d = make_uint4( \
                    pkh(bnda[it].x, bndb[it].x), pkh(bnda[it].y, bndb[it].y), \
                    pkh(bnda[it].z, bndb[it].z), pkh(bnda[it].w, bndb[it].w)); \
            } \
        } }

    BLOAD3(0);   // issue granule-0 band loads before meta (latency overlap)

    // ---- meta in registers: one sampling element per thread (tid < 288) ----
    uint4 mwp = make_uint4(0, 0, 0, 0);
    int2 mq = make_int2(r0 << 8, r0 << 8);
    int2 mi = make_int2(7, 7);
    if (tid < ME3) {
        const int t = tid >> 5, px = tid & 31, pg = pxbase + px;
        const int ty = t / 3, tx = t - ty * 3;
        const float oy = offs[((b * 18 + 2 * t    ) * Hn + h) * Wn + pg];
        const float ox = offs[((b * 18 + 2 * t + 1) * Hn + h) * Wn + pg];
        const float m  = mask[((b * KK + t) * Hn + h) * Wn + pg];
        const float py = (float)(h - PAD + ty) + oy;
        const float qx = (float)(pg - PAD + tx) + ox;
        const float fy = floorf(py), fx = floorf(qx);
        const float wy1 = py - fy, wx1 = qx - fx;
        const float wy0 = 1.f - wy1, wx0 = 1.f - wx1;
        const int y0 = (int)fy, x0 = (int)fx;
        const bool cx0 = (x0 >= 0) && (x0 < Wn);
        const bool cx1 = (x0 >= -1) && (x0 < Wn - 1);
        const float wr[2] = { wy0, wy1 };
        float wout[4]; int qout[2], iout[2];
        #pragma unroll
        for (int j = 0; j < 2; ++j) {
            const int yr = y0 + j;
            const bool rv = (yr >= 0) && (yr < Hn);
            wout[2 * j]     = (rv && cx0) ? wr[j] * wx0 * m : 0.f;
            wout[2 * j + 1] = (rv && cx1) ? wr[j] * wx1 * m : 0.f;
            int qv;
            if (!rv || (!cx0 && !cx1)) qv = r0 << 8;   // junk: w=0, reads pad
            else                       qv = (yr << 8) | (x0 + 1);
            const bool inband = (qv >> 8) >= r0 && (qv >> 8) < r0 + BANDH;
            qout[j] = inband ? qv : ~qv;
            iout[j] = ((qv >> 8) - r0) * RST + (qv & 255) + 7;
        }
        mwp = make_uint4(pkh(wout[0], wout[0]), pkh(wout[1], wout[1]),
                         pkh(wout[2], wout[2]), pkh(wout[3], wout[3]));
        mq = make_int2(qout[0], qout[1]);
        mi = make_int2(iout[0], iout[1]);
    }

    // ---- zero pband never-written gaps (4 pairs x 52) ----
    if (tid < 208) {
        const int pair = tid / 52, j = tid - pair * 52;
        const int off = (j < 8) ? j : RST * ((j - 8) >> 2) + 72 + ((j - 8) & 3);
        pband[pair * XSTP + off] = 0;
    }
    // ---- zero ash K-pad (dwords 36..47 per px, both buffers) ----
    #pragma unroll
    for (int it = 0; it < 2; ++it) {
        const int u = tid + it * BDIM;
        if (u < 768) {
            const int buf = u / 384, rem = u - buf * 384;
            const int px = rem / 12, j = rem - px * 12;
            smem[PB3_DW + buf * ASH3_DW + px * AST3 + 36 + j] = 0;
        }
    }

    BWRITE3();      // band 0 -> pband
    BLOAD3(1);      // issue granule-1 band loads
    __syncthreads();

    const int wv = tid >> 6, ln = tid & 63, quad = ln >> 4, l16 = ln & 15;
    const u16* wrow = wh3 + (size_t)(wv * 16 + l16) * KT3;   // wave o-tile: 16 rows

    // ---- sample granule 0 -> ash[0] ----
    if (tid < ME3)
        sample3(pband, smem + PB3_DW, x + (((size_t)(b * Cn)) << 12),
                mwp, mq, mi, tid);
    __syncthreads();

    f32x4 acc[2];
    acc[0] = (f32x4){0.f, 0.f, 0.f, 0.f};
    acc[1] = (f32x4){0.f, 0.f, 0.f, 0.f};

#define MSTEP3(S) { \
        const f16x8 a = *(const f16x8*)(wrow + g * KG3 + (S) * 32 + quad * 8); \
        U4H b0, b1; \
        b0.u = *(const uint4*)&ad[l16 * AST3 + (S) * 16 + quad * 4]; \
        b1.u = *(const uint4*)&ad[(16 + l16) * AST3 + (S) * 16 + quad * 4]; \
        acc[0] = __builtin_amdgcn_mfma_f32_16x16x32_f16(a, b0.h, acc[0], 0, 0, 0); \
        acc[1] = __builtin_amdgcn_mfma_f32_16x16x32_f16(a, b1.h, acc[1], 0, 0, 0); }

    // ---- pipelined granule loop: 2 barriers/granule, MFMA in BOTH segments ----
    for (int g = 0; g < NG3; ++g) {
        const u32* ad = smem + PB3_DW + (g & 1) * ASH3_DW;       // MFMA(g) source
        u32* ashN     = smem + PB3_DW + ((g + 1) & 1) * ASH3_DW; // sample(g+1) dest
        // -- segment B: band-write(g+1) || MFMA(g) step 0 --
        if (g + 1 < NG3) BWRITE3();
        MSTEP3(0);
        __syncthreads();                                          // pband(g+1) ready
        // -- segment A: band-load(g+2) || sample(g+1) || MFMA(g) steps 1-2 --
        if (g + 2 < NG3) BLOAD3(g + 2);
        if (g + 1 < NG3 && tid < ME3)
            sample3(pband, ashN,
                    x + (((size_t)(b * Cn + (g + 1) * CG3)) << 12),
                    mwp, mq, mi, tid);
        MSTEP3(1);
        MSTEP3(2);
        __syncthreads();    // ash[(g+1)&1] ready; ash[g&1]/pband reads drained
    }

    // ---- epilogue: transpose via LDS (stride 36) -> 128B full-line stores ----
    float* tr = (float*)smem;              // 128 o x 32 px = 4608 dw (fits 6352)
    #pragma unroll
    for (int nt = 0; nt < 2; ++nt)
        #pragma unroll
        for (int r = 0; r < 4; ++r) {
            const int o = wv * 16 + quad * 4 + r;
            tr[o * 36 + nt * 16 + l16] = acc[nt][r] + bias[o];
        }
    __syncthreads();
    {
        const int f = tid & 7;
        #pragma unroll
        for (int it = 0; it < 2; ++it) {
            const int o = it * 64 + (tid >> 3);
            *(float4*)&out[(((size_t)b * On + o) << 12) + h * Wn + pxbase + (f << 2)]
                = *(const float4*)&tr[o * 36 + (f << 2)];
        }
    }
#undef BLOAD3
#undef BWRITE3
#undef MSTEP3
}

// ================= fallback: proven R2 fp32 kernel (no d_ws) =================
constexpr int FBD = 256;
constexpr int FB_PXB = 32, FB_CCH = 4, FB_NCT = FB_CCH * KK, FB_MW = KK * FB_PXB;

#define FMA4(A, S, W)                          \
    A.x = fmaf((S).x, (W), A.x);               \
    A.y = fmaf((S).y, (W), A.y);               \
    A.z = fmaf((S).z, (W), A.z);               \
    A.w = fmaf((S).w, (W), A.w);

__global__ __launch_bounds__(FBD, 4)
void dcn_fb_kernel(const float* __restrict__ x,
                   const float* __restrict__ offs,
                   const float* __restrict__ mask,
                   const float* __restrict__ weight,
                   const float* __restrict__ bias,
                   float* __restrict__ out)
{
    __shared__ float wmeta[4 * FB_MW];
    __shared__ int   imeta[4 * FB_MW];
    __shared__ float ssh[FB_NCT * FB_PXB];
    __shared__ float wsh[FB_NCT * On];

    const int tid    = threadIdx.x;
    const int b      = blockIdx.x & 7;
    const int rem    = blockIdx.x >> 3;
    const int h      = rem >> 1;
    const int pxbase = (rem & 1) * FB_PXB;

    for (int e = tid; e < FB_MW; e += FBD) {
        const int t  = e >> 5;
        const int px = e & 31;
        const int pg = pxbase + px;
        const int ty = t / 3, tx = t - ty * 3;
        const float oy = offs[((b * 18 + 2 * t    ) * Hn + h) * Wn + pg];
        const float ox = offs[((b * 18 + 2 * t + 1) * Hn + h) * Wn + pg];
        const float m  = mask[((b * KK + t) * Hn + h) * Wn + pg];
        const float py = (float)(h - PAD + ty) + oy;
        const float qx = (float)(pg - PAD + tx) + ox;
        const float y0 = floorf(py), x0 = floorf(qx);
        const float wy1 = py - y0, wx1 = qx - x0;
        const float wy0 = 1.f - wy1, wx0 = 1.f - wx1;
        const float cw[4] = { wy0 * wx0, wy0 * wx1, wy1 * wx0, wy1 * wx1 };
        #pragma unroll
        for (int k = 0; k < 4; ++k) {
            const float yk = y0 + (float)(k >> 1);
            const float xk = x0 + (float)(k & 1);
            const bool valid = (yk >= 0.f) && (yk <= (float)(Hn - 1)) &&
                               (xk >= 0.f) && (xk <= (float)(Wn - 1));
            const int yc = (int)fminf(fmaxf(yk, 0.f), (float)(Hn - 1));
            const int xc = (int)fminf(fmaxf(xk, 0.f), (float)(Wn - 1));
            wmeta[k * FB_MW + e] = valid ? cw[k] * m : 0.f;
            imeta[k * FB_MW + e] = yc * Wn + xc;
        }
    }
    __syncthreads();

    const int px0 = (tid & 7) << 2;
    const int oo  = (tid >> 3) << 2;

    float4 acc[4];
    #pragma unroll
    for (int j = 0; j < 4; ++j) acc[j] = make_float4(0.f, 0.f, 0.f, 0.f);

    for (int cb = 0; cb < Cn / FB_CCH; ++cb) {
        #pragma unroll
        for (int it = 0; it < (FB_NCT * On) / FBD; ++it) {
            const int e = tid + it * FBD;
            const int r = e >> 7;
            const int o = e & 127;
            wsh[r * On + o] = weight[o * (Cn * KK) + cb * FB_NCT + r];
        }
        for (int e = tid; e < FB_NCT * FB_PXB; e += FBD) {
            const int px = e & 31;
            const int ct = e >> 5;
            const int c  = ct / 9;
            const int mb = (ct - c * 9) * FB_PXB + px;
            const float* xp = x + (((b * Cn) + cb * FB_CCH + c) << 12);
            float v =  wmeta[mb]              * xp[imeta[mb]];
            v = fmaf(wmeta[FB_MW     + mb], xp[imeta[FB_MW     + mb]], v);
            v = fmaf(wmeta[2 * FB_MW + mb], xp[imeta[2 * FB_MW + mb]], v);
            v = fmaf(wmeta[3 * FB_MW + mb], xp[imeta[3 * FB_MW + mb]], v);
            ssh[ct * FB_PXB + px] = v;
        }
        __syncthreads();

        #pragma unroll 6
        for (int ct = 0; ct < FB_NCT; ++ct) {
            const float4 sv = *(const float4*)&ssh[ct * FB_PXB + px0];
            const float4 wa = *(const float4*)&wsh[ct * On + oo];
            FMA4(acc[0], sv, wa.x);
            FMA4(acc[1], sv, wa.y);
            FMA4(acc[2], sv, wa.z);
            FMA4(acc[3], sv, wa.w);
        }
        __syncthreads();
    }

    #pragma unroll
    for (int j = 0; j < 4; ++j) {
        const float bv = bias[oo + j];
        float4 r = acc[j];
        r.x += bv; r.y += bv; r.z += bv; r.w += bv;
        *(float4*)&out[((b * On + oo + j) * Hn + h) * Wn + pxbase + px0] = r;
    }
}

extern "C" void kernel_launch(void* const* d_in, const int* in_sizes, int n_in,
                              void* d_out, int out_size, void* d_ws, size_t ws_size,
                              hipStream_t stream) {
    const float* x      = (const float*)d_in[0];
    const float* offs   = (const float*)d_in[1];
    const float* mask   = (const float*)d_in[2];
    const float* weight = (const float*)d_in[3];
    const float* bias   = (const float*)d_in[4];
    float* out = (float*)d_out;

    if (d_ws != nullptr && ws_size >= WH3_BYTES) {
        u16* wh3 = (u16*)d_ws;
        wprep3_kernel<<<dim3(On), dim3(256), 0, stream>>>(weight, wh3);
        dcn_cg8_kernel<<<dim3(2 * Bn * Hn), dim3(BDIM), 0, stream>>>(
            x, offs, mask, wh3, bias, out);
    } else {
        dcn_fb_kernel<<<dim3(Bn * Hn * 2), dim3(FBD), 0, stream>>>(
            x, offs, mask, weight, bias, out);
    }
}

// Round 11
// 156.133 us; speedup vs baseline: 1.2055x; 1.0921x over previous
//
#include <hip/hip_runtime.h>
#include <math.h>

// DCN v2: B=8, C=128, O=128, H=W=64, k=3, dil=1, dg=1, stride=1, pad=1.
// R19 = R18 resubmitted verbatim (R18 died to GPU-acquisition timeout
// before running). One change vs R17: __launch_bounds__(512,8) -> (512,6).
// R17 post-mortem: the 8-waves/EU bound capped VGPRs at 64; allocator
// spilled (VGPR_Count=32, WRITE_SIZE 16384->63488 KB = +46MB scratch
// round-trips in the hot loop) -> 110us despite 51% occupancy. (512,6)
// caps at ~85 VGPRs: natural live set ~60-75 fits spill-free; occupancy
// then = 3 blocks/CU (24 waves, 1.5x R12) via the small 25.4KB LDS.
// Design (occupancy restructure of proven R12 fused pipeline):
//   PXB=32, CG=8, grid 1024. pband 4 pairs x 756 = 12.1KB; ash 2 x 32x52 =
//   13.3KB -> LDS 25.4KB. acc[2] (16o x 32px per wave, single A-row ->
//   A reuse x2), K/granule = 72 real padded to 96 = 3 exact MFMA K-steps;
//   ash stride 52 (=20 mod 32, proven 2-way-free b128). Sampling = 288
//   elems = 1/thread; waves 5-7 skip sampling and enter MFMA early.
// Fallback: proven R2 fp32 kernel (no ws).
constexpr int Bn = 8, Cn = 128, On = 128, Hn = 64, Wn = 64;
constexpr int KK = 9, PAD = 1;
constexpr int BDIM = 512;                 // 8 waves
constexpr int BANDH = 11;                 // band rows (h-5 .. h+5)
constexpr int RST  = 68;                  // pband row stride (dwords)
constexpr int XSTP = 756;                 // pband pair stride (dwords)

// ---- geometry ----
constexpr int PXB3 = 32;                  // pixels per block (half row)
constexpr int CG3  = 8,  NG3 = 16;        // 8 channels per granule, 16 granules
constexpr int KG3  = 96;                  // padded K per granule (72 real)
constexpr int KT3  = NG3 * KG3;           // 1536
constexpr int AST3 = 52;                  // ash px stride (dw), 20 mod 32
constexpr int ME3  = KK * PXB3;           // 288 sampling elements
constexpr int PB3_DW  = 4 * XSTP;         // 3024
constexpr int ASH3_DW = PXB3 * AST3;      // 1664
constexpr int SM3_DW  = PB3_DW + 2 * ASH3_DW;   // 6352 dw = 25,408 B
constexpr int BU3  = BANDH * 64;          // 704 band units (4 pairs x 11 x 16)
constexpr size_t WH3_BYTES = (size_t)On * KT3 * 2;   // 393,216 B

typedef __attribute__((ext_vector_type(2))) _Float16 h2;      // arithmetic
typedef __attribute__((ext_vector_type(8))) __fp16   f16x8;   // MFMA operand
typedef __attribute__((ext_vector_type(4))) float f32x4;
typedef unsigned short u16;
typedef unsigned int u32;

union UH  { u32 u; h2 h; };
union U4H { uint4 u; f16x8 h; };

__device__ __forceinline__ u32 pkh(float a, float b) {  // low16 = f16(a), RTZ
    union { decltype(__builtin_amdgcn_cvt_pkrtz(0.f, 0.f)) p; u32 u; } t;
    t.p = __builtin_amdgcn_cvt_pkrtz(a, b);
    return t.u;
}
__device__ __forceinline__ h2 bch(u32 w) { UH t; t.u = w; return t.h; }
__device__ __forceinline__ u16 f2h(float f) {           // RNE f32->f16
    union { _Float16 h; u16 u; } v; v.h = (_Float16)f; return v.u;
}

// weight [O][C*9] fp32 -> wh3 [O][KT3=1536] f16, k' = g*96 + t*8 + cl
// (g = c>>3, cl = c&7); k' in [g*96+72, g*96+96) zero pad.
__global__ void wprep3_kernel(const float* __restrict__ w, u16* __restrict__ wh3) {
    __shared__ u16 tmp[KT3];
    const int tid = threadIdx.x, o = blockIdx.x;
    for (int e = tid; e < 384; e += 256) {   // zero pads: 16 granules x 24
        const int g = e / 24, j = e - g * 24;
        tmp[g * 96 + 72 + j] = 0;
    }
    for (int k = tid; k < Cn * KK; k += 256) {
        const int c = k / 9, t = k - 9 * c;
        tmp[(c >> 3) * 96 + t * 8 + (c & 7)] = f2h(w[o * (Cn * KK) + k]);
    }
    __syncthreads();
    u32* dst = (u32*)(wh3 + (size_t)o * KT3);
    for (int e = tid; e < KT3 / 2; e += 256) dst[e] = ((u32*)tmp)[e];
}

// sampling of one (tap,px) element for one 8-channel granule.
__device__ __forceinline__ void sample3(const u32* __restrict__ pband,
                                        u32* __restrict__ ashW,
                                        const float* __restrict__ xg,
                                        const uint4 wp, const int2 q,
                                        const int2 ix, const int tid)
{
    const int t = tid >> 5, px = tid & 31;
    u32 avp[4];
    if (!__any((q.x | q.y) < 0)) {           // all active corners in band
        const u32* p0 = pband + ix.x;
        const u32* p1 = pband + ix.y;
        const h2 w0 = bch(wp.x), w1 = bch(wp.y), w2 = bch(wp.z), w3 = bch(wp.w);
        #pragma unroll
        for (int c2 = 0; c2 < 4; ++c2) {
            const h2 vt0 = bch(p0[c2 * XSTP]), vt1 = bch(p0[c2 * XSTP + 1]);
            const h2 vb0 = bch(p1[c2 * XSTP]), vb1 = bch(p1[c2 * XSTP + 1]);
            const h2 r = w0 * vt0 + w1 * vt1 + w2 * vb0 + w3 * vb1;
            UH o; o.h = r; avp[c2] = o.u;
        }
    } else {                                  // rare: clamped global reads
        const float fw0 = (float)bch(wp.x)[0], fw1 = (float)bch(wp.y)[0];
        const float fw2 = (float)bch(wp.z)[0], fw3 = (float)bch(wp.w)[0];
        const int qx = q.x < 0 ? ~q.x : q.x;
        const int qy = q.y < 0 ? ~q.y : q.y;
        const int yrx = qx >> 8, yry = qy >> 8;
        const int xx = (qx & 255) - 1, xy = (qy & 255) - 1;
        const int ax0 = max(xx, 0), ax1 = min(xx + 1, Wn - 1);
        const int ay0 = max(xy, 0), ay1 = min(xy + 1, Wn - 1);
        #pragma unroll
        for (int c2 = 0; c2 < 4; ++c2) {
            float v2[2];
            #pragma unroll
            for (int sb = 0; sb < 2; ++sb) {
                const float* gc = xg + ((2 * c2 + sb) << 12);
                const float t0 = gc[yrx * Wn + ax0], t1 = gc[yrx * Wn + ax1];
                const float b0 = gc[yry * Wn + ay0], b1 = gc[yry * Wn + ay1];
                v2[sb] = fmaf(fw0, t0, fmaf(fw1, t1, fmaf(fw2, b0, fw3 * b1)));
            }
            avp[c2] = pkh(v2[0], v2[1]);
        }
    }
    *(uint4*)(ashW + px * AST3 + t * 4) = make_uint4(avp[0], avp[1], avp[2], avp[3]);
}

__global__ __launch_bounds__(BDIM, 6)
void dcn_cg8_kernel(const float* __restrict__ x,
                    const float* __restrict__ offs,
                    const float* __restrict__ mask,
                    const u16*   __restrict__ wh3,
                    const float* __restrict__ bias,
                    float* __restrict__ out)
{
    __shared__ __align__(16) u32 smem[SM3_DW];   // pband | ash0 | ash1
    u32* const pband = smem;

    const int tid    = threadIdx.x;
    const int b      = blockIdx.x & 7;           // batch <-> XCD affinity
    const int h      = (blockIdx.x >> 3) & 63;
    const int pxbase = (blockIdx.x >> 9) * PXB3;
    const int r0     = min(max(h - 5, 0), Hn - BANDH);

    float4 bnda[2], bndb[2];
#define BLOAD3(GCH) { \
        _Pragma("unroll") \
        for (int it = 0; it < 2; ++it) { \
            const int u = tid + it * BDIM; \
            if (u < BU3) { \
                const int px4 = u & 15, pair = (u >> 4) & 3, row = u >> 6; \
                const float* bp = x + (((size_t)(b * Cn + (GCH) * CG3 + 2 * pair)) << 12) \
                                  + (r0 + row) * Wn + (px4 << 2); \
                bnda[it] = *(const float4*)bp; \
                bndb[it] = *(const float4*)(bp + 4096); \
            } \
        } }
#define BWRITE3() { \
        _Pragma("unroll") \
        for (int it = 0; it < 2; ++it) { \
            const int u = tid + it * BDIM; \
            if (u < BU3) { \
                const int px4 = u & 15, pair = (u >> 4) & 3, row = u >> 6; \
                u32* d = &pband[pair * XSTP + row * RST + 8 + (px4 << 2)]; \
                *(uint4*)d = make_uint4( \
                    pkh(bnda[it].x, bndb[it].x), pkh(bnda[it].y, bndb[it].y), \
                    pkh(bnda[it].z, bndb[it].z), pkh(bnda[it].w, bndb[it].w)); \
            } \
        } }

    BLOAD3(0);   // issue granule-0 band loads before meta (latency overlap)

    // ---- meta in registers: one sampling element per thread (tid < 288) ----
    uint4 mwp = make_uint4(0, 0, 0, 0);
    int2 mq = make_int2(r0 << 8, r0 << 8);
    int2 mi = make_int2(7, 7);
    if (tid < ME3) {
        const int t = tid >> 5, px = tid & 31, pg = pxbase + px;
        const int ty = t / 3, tx = t - ty * 3;
        const float oy = offs[((b * 18 + 2 * t    ) * Hn + h) * Wn + pg];
        const float ox = offs[((b * 18 + 2 * t + 1) * Hn + h) * Wn + pg];
        const float m  = mask[((b * KK + t) * Hn + h) * Wn + pg];
        const float py = (float)(h - PAD + ty) + oy;
        const float qx = (float)(pg - PAD + tx) + ox;
        const float fy = floorf(py), fx = floorf(qx);
        const float wy1 = py - fy, wx1 = qx - fx;
        const float wy0 = 1.f - wy1, wx0 = 1.f - wx1;
        const int y0 = (int)fy, x0 = (int)fx;
        const bool cx0 = (x0 >= 0) && (x0 < Wn);
        const bool cx1 = (x0 >= -1) && (x0 < Wn - 1);
        const float wr[2] = { wy0, wy1 };
        float wout[4]; int qout[2], iout[2];
        #pragma unroll
        for (int j = 0; j < 2; ++j) {
            const int yr = y0 + j;
            const bool rv = (yr >= 0) && (yr < Hn);
            wout[2 * j]     = (rv && cx0) ? wr[j] * wx0 * m : 0.f;
            wout[2 * j + 1] = (rv && cx1) ? wr[j] * wx1 * m : 0.f;
            int qv;
            if (!rv || (!cx0 && !cx1)) qv = r0 << 8;   // junk: w=0, reads pad
            else                       qv = (yr << 8) | (x0 + 1);
            const bool inband = (qv >> 8) >= r0 && (qv >> 8) < r0 + BANDH;
            qout[j] = inband ? qv : ~qv;
            iout[j] = ((qv >> 8) - r0) * RST + (qv & 255) + 7;
        }
        mwp = make_uint4(pkh(wout[0], wout[0]), pkh(wout[1], wout[1]),
                         pkh(wout[2], wout[2]), pkh(wout[3], wout[3]));
        mq = make_int2(qout[0], qout[1]);
        mi = make_int2(iout[0], iout[1]);
    }

    // ---- zero pband never-written gaps (4 pairs x 52) ----
    if (tid < 208) {
        const int pair = tid / 52, j = tid - pair * 52;
        const int off = (j < 8) ? j : RST * ((j - 8) >> 2) + 72 + ((j - 8) & 3);
        pband[pair * XSTP + off] = 0;
    }
    // ---- zero ash K-pad (dwords 36..47 per px, both buffers) ----
    #pragma unroll
    for (int it = 0; it < 2; ++it) {
        const int u = tid + it * BDIM;
        if (u < 768) {
            const int buf = u / 384, rem = u - buf * 384;
            const int px = rem / 12, j = rem - px * 12;
            smem[PB3_DW + buf * ASH3_DW + px * AST3 + 36 + j] = 0;
        }
    }

    BWRITE3();      // band 0 -> pband
    BLOAD3(1);      // issue granule-1 band loads
    __syncthreads();

    const int wv = tid >> 6, ln = tid & 63, quad = ln >> 4, l16 = ln & 15;
    const u16* wrow = wh3 + (size_t)(wv * 16 + l16) * KT3;   // wave o-tile: 16 rows

    // ---- sample granule 0 -> ash[0] ----
    if (tid < ME3)
        sample3(pband, smem + PB3_DW, x + (((size_t)(b * Cn)) << 12),
                mwp, mq, mi, tid);
    __syncthreads();

    f32x4 acc[2];
    acc[0] = (f32x4){0.f, 0.f, 0.f, 0.f};
    acc[1] = (f32x4){0.f, 0.f, 0.f, 0.f};

#define MSTEP3(S) { \
        const f16x8 a = *(const f16x8*)(wrow + g * KG3 + (S) * 32 + quad * 8); \
        U4H b0, b1; \
        b0.u = *(const uint4*)&ad[l16 * AST3 + (S) * 16 + quad * 4]; \
        b1.u = *(const uint4*)&ad[(16 + l16) * AST3 + (S) * 16 + quad * 4]; \
        acc[0] = __builtin_amdgcn_mfma_f32_16x16x32_f16(a, b0.h, acc[0], 0, 0, 0); \
        acc[1] = __builtin_amdgcn_mfma_f32_16x16x32_f16(a, b1.h, acc[1], 0, 0, 0); }

    // ---- pipelined granule loop: 2 barriers/granule, MFMA in BOTH segments ----
    for (int g = 0; g < NG3; ++g) {
        const u32* ad = smem + PB3_DW + (g & 1) * ASH3_DW;       // MFMA(g) source
        u32* ashN     = smem + PB3_DW + ((g + 1) & 1) * ASH3_DW; // sample(g+1) dest
        // -- segment B: band-write(g+1) || MFMA(g) step 0 --
        if (g + 1 < NG3) BWRITE3();
        MSTEP3(0);
        __syncthreads();                                          // pband(g+1) ready
        // -- segment A: band-load(g+2) || sample(g+1) || MFMA(g) steps 1-2 --
        if (g + 2 < NG3) BLOAD3(g + 2);
        if (g + 1 < NG3 && tid < ME3)
            sample3(pband, ashN,
                    x + (((size_t)(b * Cn + (g + 1) * CG3)) << 12),
                    mwp, mq, mi, tid);
        MSTEP3(1);
        MSTEP3(2);
        __syncthreads();    // ash[(g+1)&1] ready; ash[g&1]/pband reads drained
    }

    // ---- epilogue: transpose via LDS (stride 36) -> 128B full-line stores ----
    float* tr = (float*)smem;              // 128 o x 32 px = 4608 dw (fits 6352)
    #pragma unroll
    for (int nt = 0; nt < 2; ++nt)
        #pragma unroll
        for (int r = 0; r < 4; ++r) {
            const int o = wv * 16 + quad * 4 + r;
            tr[o * 36 + nt * 16 + l16] = acc[nt][r] + bias[o];
        }
    __syncthreads();
    {
        const int f = tid & 7;
        #pragma unroll
        for (int it = 0; it < 2; ++it) {
            const int o = it * 64 + (tid >> 3);
            *(float4*)&out[(((size_t)b * On + o) << 12) + h * Wn + pxbase + (f << 2)]
                = *(const float4*)&tr[o * 36 + (f << 2)];
        }
    }
#undef BLOAD3
#undef BWRITE3
#undef MSTEP3
}

// ================= fallback: proven R2 fp32 kernel (no d_ws) =================
constexpr int FBD = 256;
constexpr int FB_PXB = 32, FB_CCH = 4, FB_NCT = FB_CCH * KK, FB_MW = KK * FB_PXB;

#define FMA4(A, S, W)                          \
    A.x = fmaf((S).x, (W), A.x);               \
    A.y = fmaf((S).y, (W), A.y);               \
    A.z = fmaf((S).z, (W), A.z);               \
    A.w = fmaf((S).w, (W), A.w);

__global__ __launch_bounds__(FBD, 4)
void dcn_fb_kernel(const float* __restrict__ x,
                   const float* __restrict__ offs,
                   const float* __restrict__ mask,
                   const float* __restrict__ weight,
                   const float* __restrict__ bias,
                   float* __restrict__ out)
{
    __shared__ float wmeta[4 * FB_MW];
    __shared__ int   imeta[4 * FB_MW];
    __shared__ float ssh[FB_NCT * FB_PXB];
    __shared__ float wsh[FB_NCT * On];

    const int tid    = threadIdx.x;
    const int b      = blockIdx.x & 7;
    const int rem    = blockIdx.x >> 3;
    const int h      = rem >> 1;
    const int pxbase = (rem & 1) * FB_PXB;

    for (int e = tid; e < FB_MW; e += FBD) {
        const int t  = e >> 5;
        const int px = e & 31;
        const int pg = pxbase + px;
        const int ty = t / 3, tx = t - ty * 3;
        const float oy = offs[((b * 18 + 2 * t    ) * Hn + h) * Wn + pg];
        const float ox = offs[((b * 18 + 2 * t + 1) * Hn + h) * Wn + pg];
        const float m  = mask[((b * KK + t) * Hn + h) * Wn + pg];
        const float py = (float)(h - PAD + ty) + oy;
        const float qx = (float)(pg - PAD + tx) + ox;
        const float y0 = floorf(py), x0 = floorf(qx);
        const float wy1 = py - y0, wx1 = qx - x0;
        const float wy0 = 1.f - wy1, wx0 = 1.f - wx1;
        const float cw[4] = { wy0 * wx0, wy0 * wx1, wy1 * wx0, wy1 * wx1 };
        #pragma unroll
        for (int k = 0; k < 4; ++k) {
            const float yk = y0 + (float)(k >> 1);
            const float xk = x0 + (float)(k & 1);
            const bool valid = (yk >= 0.f) && (yk <= (float)(Hn - 1)) &&
                               (xk >= 0.f) && (xk <= (float)(Wn - 1));
            const int yc = (int)fminf(fmaxf(yk, 0.f), (float)(Hn - 1));
            const int xc = (int)fminf(fmaxf(xk, 0.f), (float)(Wn - 1));
            wmeta[k * FB_MW + e] = valid ? cw[k] * m : 0.f;
            imeta[k * FB_MW + e] = yc * Wn + xc;
        }
    }
    __syncthreads();

    const int px0 = (tid & 7) << 2;
    const int oo  = (tid >> 3) << 2;

    float4 acc[4];
    #pragma unroll
    for (int j = 0; j < 4; ++j) acc[j] = make_float4(0.f, 0.f, 0.f, 0.f);

    for (int cb = 0; cb < Cn / FB_CCH; ++cb) {
        #pragma unroll
        for (int it = 0; it < (FB_NCT * On) / FBD; ++it) {
            const int e = tid + it * FBD;
            const int r = e >> 7;
            const int o = e & 127;
            wsh[r * On + o] = weight[o * (Cn * KK) + cb * FB_NCT + r];
        }
        for (int e = tid; e < FB_NCT * FB_PXB; e += FBD) {
            const int px = e & 31;
            const int ct = e >> 5;
            const int c  = ct / 9;
            const int mb = (ct - c * 9) * FB_PXB + px;
            const float* xp = x + (((b * Cn) + cb * FB_CCH + c) << 12);
            float v =  wmeta[mb]              * xp[imeta[mb]];
            v = fmaf(wmeta[FB_MW     + mb], xp[imeta[FB_MW     + mb]], v);
            v = fmaf(wmeta[2 * FB_MW + mb], xp[imeta[2 * FB_MW + mb]], v);
            v = fmaf(wmeta[3 * FB_MW + mb], xp[imeta[3 * FB_MW + mb]], v);
            ssh[ct * FB_PXB + px] = v;
        }
        __syncthreads();

        #pragma unroll 6
        for (int ct = 0; ct < FB_NCT; ++ct) {
            const float4 sv = *(const float4*)&ssh[ct * FB_PXB + px0];
            const float4 wa = *(const float4*)&wsh[ct * On + oo];
            FMA4(acc[0], sv, wa.x);
            FMA4(acc[1], sv, wa.y);
            FMA4(acc[2], sv, wa.z);
            FMA4(acc[3], sv, wa.w);
        }
        __syncthreads();
    }

    #pragma unroll
    for (int j = 0; j < 4; ++j) {
        const float bv = bias[oo + j];
        float4 r = acc[j];
        r.x += bv; r.y += bv; r.z += bv; r.w += bv;
        *(float4*)&out[((b * On + oo + j) * Hn + h) * Wn + pxbase + px0] = r;
    }
}

extern "C" void kernel_launch(void* const* d_in, const int* in_sizes, int n_in,
                              void* d_out, int out_size, void* d_ws, size_t ws_size,
                              hipStream_t stream) {
    const float* x      = (const float*)d_in[0];
    const float* offs   = (const float*)d_in[1];
    const float* mask   = (const float*)d_in[2];
    const float* weight = (const float*)d_in[3];
    const float* bias   = (const float*)d_in[4];
    float* out = (float*)d_out;

    if (d_ws != nullptr && ws_size >= WH3_BYTES) {
        u16* wh3 = (u16*)d_ws;
        wprep3_kernel<<<dim3(On), dim3(256), 0, stream>>>(weight, wh3);
        dcn_cg8_kernel<<<dim3(2 * Bn * Hn), dim3(BDIM), 0, stream>>>(
            x, offs, mask, wh3, bias, out);
    } else {
        dcn_fb_kernel<<<dim3(Bn * Hn * 2), dim3(FBD), 0, stream>>>(
            x, offs, mask, weight, bias, out);
    }
}

// Round 12
// 140.310 us; speedup vs baseline: 1.3414x; 1.1128x over previous
//
#include <hip/hip_runtime.h>
#include <math.h>

// DCN v2: B=8, C=128, O=128, H=W=64, k=3, dil=1, dg=1, stride=1, pad=1.
// R20 = R12 with ash single-buffered for 3 blocks/CU.
// R19 post-mortem: cg8 small-block restructure dead (spills at ANY cap,
// 2x band redundancy, 2x barriers). R12 (70.9us) remains best; it is
// latency-bound at 2 blocks/CU. This round: keep R12's proven code but
// drop the ash double buffer -> LDS 67.2KB -> 45.7KB -> 3 blocks/CU
// (24 waves, +50%). Pipeline: segA = sample(g); barrier; segB =
// band-write(g+1) || band-load(g+2) || MFMA(g) x5; barrier. Intra-block
// sample||MFMA overlap is traded for CU-level cross-block overlap
// (m114: MFMA+VALU pipes co-schedule across waves). Registers DROP vs
// R12 (no A-prefetch held across barriers) -> launch_bounds(512,4), no
// spill risk; LDS is the occupancy limiter by design.
constexpr int Bn = 8, Cn = 128, On = 128, Hn = 64, Wn = 64;
constexpr int KK = 9, PAD = 1;
constexpr int BDIM = 512;                 // 8 waves
constexpr int PXB  = 64;                  // full row per block
constexpr int CG = 16, NG = Cn / CG;      // 8 channel granules
constexpr int KG = 160, KTOT = NG * KG;   // 1280 (144 real + 16 pad per granule)
constexpr int BANDH = 11;                 // band rows (h-5 .. h+5)
constexpr int RST  = 68;                  // pband row stride (dwords)
constexpr int XSTP = 756;                 // pband pair stride (dwords)
constexpr int AST  = 84;                  // ash px stride (dwords), 16B-aligned
constexpr int ME   = KK * PXB;            // 576 sampling elements
constexpr int PB_DW  = 8 * XSTP;          // 6048
constexpr int ASH_DW = PXB * AST;         // 5376
constexpr int SM_DW  = PB_DW + ASH_DW;    // 11424 dw = 45,696 B (3 blocks/CU)
constexpr int BUNITS = BANDH * 128;       // 1408 band load/write units
constexpr size_t WH_BYTES = (size_t)On * KTOT * 2;   // 327,680 B

typedef __attribute__((ext_vector_type(2))) _Float16 h2;      // arithmetic
typedef __attribute__((ext_vector_type(8))) __fp16   f16x8;   // MFMA operand
typedef __attribute__((ext_vector_type(4))) float f32x4;
typedef unsigned short u16;
typedef unsigned int u32;

union UH  { u32 u; h2 h; };
union U4H { uint4 u; f16x8 h; };

__device__ __forceinline__ u32 pkh(float a, float b) {  // low16 = f16(a), RTZ
    union { decltype(__builtin_amdgcn_cvt_pkrtz(0.f, 0.f)) p; u32 u; } t;
    t.p = __builtin_amdgcn_cvt_pkrtz(a, b);
    return t.u;
}
__device__ __forceinline__ h2 bch(u32 w) { UH t; t.u = w; return t.h; }
__device__ __forceinline__ u16 f2h(float f) {           // RNE f32->f16
    union { _Float16 h; u16 u; } v; v.h = (_Float16)f; return v.u;
}

// weight [O][C*9] fp32 -> wh [O][KTOT] f16, k' = g*KG + t*16 + cl.
__global__ void wprep_kernel(const float* __restrict__ w, u16* __restrict__ wh) {
    __shared__ u32 tmpw[KTOT / 2];
    u16* tmp = (u16*)tmpw;
    const int tid = threadIdx.x, o = blockIdx.x;
    if (tid < 64)    // zero pad slices k=144..159 of each granule (dwords 72..79)
        tmpw[(tid >> 3) * 80 + 72 + (tid & 7)] = 0;
    for (int k = tid; k < Cn * KK; k += 256) {
        const int c = k / 9, t = k - 9 * c;
        tmp[(c >> 4) * KG + t * 16 + (c & 15)] = f2h(w[o * (Cn * KK) + k]);
    }
    __syncthreads();
    u32* dst = (u32*)(wh + (size_t)o * KTOT);
    for (int e = tid; e < KTOT / 2; e += 256) dst[e] = tmpw[e];
}

// sampling of one (tap,px) element for one 16-channel granule.
__device__ __forceinline__ void do_sample(const u32* __restrict__ pband,
                                          u32* __restrict__ ashW,
                                          const float* __restrict__ xg,
                                          const uint4 wp, const int2 q,
                                          const int2 ix, const int e)
{
    const int t = e >> 6, px = e & 63;
    u32 avp[8];
    if (!__any((q.x | q.y) < 0)) {           // all corners of wave in band
        const u32* p0 = pband + ix.x;
        const u32* p1 = pband + ix.y;
        const h2 w0 = bch(wp.x), w1 = bch(wp.y), w2 = bch(wp.z), w3 = bch(wp.w);
        #pragma unroll
        for (int c2 = 0; c2 < 8; ++c2) {
            const h2 vt0 = bch(p0[c2 * XSTP]), vt1 = bch(p0[c2 * XSTP + 1]);
            const h2 vb0 = bch(p1[c2 * XSTP]), vb1 = bch(p1[c2 * XSTP + 1]);
            const h2 r = w0 * vt0 + w1 * vt1 + w2 * vb0 + w3 * vb1;
            UH o; o.h = r; avp[c2] = o.u;
        }
    } else {                                  // rare: clamped global reads
        const float fw0 = (float)bch(wp.x)[0], fw1 = (float)bch(wp.y)[0];
        const float fw2 = (float)bch(wp.z)[0], fw3 = (float)bch(wp.w)[0];
        const int qx = q.x < 0 ? ~q.x : q.x;
        const int qy = q.y < 0 ? ~q.y : q.y;
        const int yrx = qx >> 8, yry = qy >> 8;
        const int xx = (qx & 255) - 1, xy = (qy & 255) - 1;
        const int ax0 = max(xx, 0), ax1 = min(xx + 1, Wn - 1);
        const int ay0 = max(xy, 0), ay1 = min(xy + 1, Wn - 1);
        #pragma unroll
        for (int c2 = 0; c2 < 8; ++c2) {
            float v2[2];
            #pragma unroll
            for (int sb = 0; sb < 2; ++sb) {
                const float* gc = xg + ((2 * c2 + sb) << 12);
                const float t0 = gc[yrx * Wn + ax0], t1 = gc[yrx * Wn + ax1];
                const float b0 = gc[yry * Wn + ay0], b1 = gc[yry * Wn + ay1];
                v2[sb] = fmaf(fw0, t0, fmaf(fw1, t1, fmaf(fw2, b0, fw3 * b1)));
            }
            avp[c2] = pkh(v2[0], v2[1]);
        }
    }
    u32* d = ashW + px * AST + t * 8;
    *(uint4*)&d[0] = make_uint4(avp[0], avp[1], avp[2], avp[3]);
    *(uint4*)&d[4] = make_uint4(avp[4], avp[5], avp[6], avp[7]);
}

__global__ __launch_bounds__(BDIM, 4)
void dcn_mfma_kernel(const float* __restrict__ x,
                     const float* __restrict__ offs,
                     const float* __restrict__ mask,
                     const u16*   __restrict__ wh,
                     const float* __restrict__ bias,
                     float* __restrict__ out)
{
    __shared__ __align__(16) u32 smem[SM_DW];   // pband | ash (single)
    u32* const pband = smem;
    u32* const ash   = smem + PB_DW;

    const int tid = threadIdx.x;
    const int b   = blockIdx.x & 7;             // batch <-> XCD affinity
    const int h   = blockIdx.x >> 3;
    const int r0  = min(max(h - 5, 0), Hn - BANDH);

    const int s_px4 = tid & 15, s_pair = (tid >> 4) & 7;

    float4 bnda[3], bndb[3];
#define BLOAD(GCH) { \
        _Pragma("unroll") \
        for (int it = 0; it < 3; ++it) { \
            const int u = tid + it * BDIM; \
            if (u < BUNITS) { \
                const int row = u >> 7; \
                const float* bp = x + (((size_t)(b * Cn + (GCH) * CG + 2 * s_pair)) << 12) \
                                  + (r0 + row) * Wn + (s_px4 << 2); \
                bnda[it] = *(const float4*)bp; \
                bndb[it] = *(const float4*)(bp + 4096); \
            } \
        } }
#define BWRITE() { \
        _Pragma("unroll") \
        for (int it = 0; it < 3; ++it) { \
            const int u = tid + it * BDIM; \
            if (u < BUNITS) { \
                const int row = u >> 7; \
                u32* d = &pband[s_pair * XSTP + row * RST + 8 + (s_px4 << 2)]; \
                *(uint4*)d = make_uint4( \
                    pkh(bnda[it].x, bndb[it].x), pkh(bnda[it].y, bndb[it].y), \
                    pkh(bnda[it].z, bndb[it].z), pkh(bnda[it].w, bndb[it].w)); \
            } \
        } }

    BLOAD(0);   // issue granule-0 band loads before meta (latency overlap)

    // ---- meta in registers: packed f16 weights mwp, coord code mq, index mi ----
    uint4 mwp[2]; int2 mq[2]; int2 mi[2];
    #pragma unroll
    for (int it = 0; it < 2; ++it) {
        mwp[it] = make_uint4(0, 0, 0, 0);
        mq[it] = make_int2(r0 << 8, r0 << 8);
        mi[it] = make_int2(7, 7);
        const int e = tid + it * BDIM;
        if (e < ME) {
            const int t = e >> 6, px = e & 63;
            const int ty = t / 3, tx = t - ty * 3;
            const float oy = offs[((b * 18 + 2 * t    ) * Hn + h) * Wn + px];
            const float ox = offs[((b * 18 + 2 * t + 1) * Hn + h) * Wn + px];
            const float m  = mask[((b * KK + t) * Hn + h) * Wn + px];
            const float py = (float)(h - PAD + ty) + oy;
            const float qx = (float)(px - PAD + tx) + ox;
            const float fy = floorf(py), fx = floorf(qx);
            const float wy1 = py - fy, wx1 = qx - fx;
            const float wy0 = 1.f - wy1, wx0 = 1.f - wx1;
            const int y0 = (int)fy, x0 = (int)fx;
            const bool cx0 = (x0 >= 0) && (x0 < Wn);
            const bool cx1 = (x0 >= -1) && (x0 < Wn - 1);
            const float wr[2] = { wy0, wy1 };
            float wout[4]; int qout[2], iout[2];
            #pragma unroll
            for (int j = 0; j < 2; ++j) {
                const int yr = y0 + j;
                const bool rv = (yr >= 0) && (yr < Hn);
                wout[2 * j]     = (rv && cx0) ? wr[j] * wx0 * m : 0.f;
                wout[2 * j + 1] = (rv && cx1) ? wr[j] * wx1 * m : 0.f;
                int qv;
                if (!rv || (!cx0 && !cx1)) qv = r0 << 8;   // junk: w=0, reads pad
                else                       qv = (yr << 8) | (x0 + 1);
                const bool inband = (qv >> 8) >= r0 && (qv >> 8) < r0 + BANDH;
                qout[j] = inband ? qv : ~qv;
                iout[j] = ((qv >> 8) - r0) * RST + (qv & 255) + 7;
            }
            mwp[it] = make_uint4(pkh(wout[0], wout[0]), pkh(wout[1], wout[1]),
                                 pkh(wout[2], wout[2]), pkh(wout[3], wout[3]));
            mq[it] = make_int2(qout[0], qout[1]);
            mi[it] = make_int2(iout[0], iout[1]);
        }
    }

    // ---- zero pband never-written gaps (NaN guard) + ash k-pad chunks ----
    if (tid < 416) {     // per pair: dwords 0..7 and 68r+72..75 (r=0..10)
        const int pair = tid / 52, j = tid - pair * 52;
        const int off = (j < 8) ? j : RST * ((j - 8) >> 2) + 72 + ((j - 8) & 3);
        pband[pair * XSTP + off] = 0;
    }
    // single ash buffer: 64 px x dwords 72..79
    ash[(tid >> 3) * AST + 72 + (tid & 7)] = 0;    // tid<512 covers all 64 px

    BWRITE();       // band 0 -> pband
    BLOAD(1);       // issue granule-1 band loads
    __syncthreads();

    const int wv = tid >> 6, ln = tid & 63, quad = ln >> 4, l16 = ln & 15;
    const int mrow = wv >> 1, ncol = wv & 1;            // 4x2 wave tiling
    const u16* wrow0 = wh + (size_t)(mrow * 32 + l16) * KTOT;
    const int npx0 = ncol * 32 + l16, npx1 = npx0 + 16;

    f32x4 acc[2][2];
    #pragma unroll
    for (int mt = 0; mt < 2; ++mt)
        #pragma unroll
        for (int nt = 0; nt < 2; ++nt) acc[mt][nt] = (f32x4){0.f, 0.f, 0.f, 0.f};

#define MSTEP(S) { \
        const int kg = g * KG + (S) * 32 + quad * 8; \
        const f16x8 a0 = *(const f16x8*)(wrow0 + kg); \
        const f16x8 a1 = *(const f16x8*)(wrow0 + 16 * KTOT + kg); \
        const int kd = (S) * 16 + quad * 4; \
        U4H b0, b1; \
        b0.u = *(const uint4*)&ash[npx0 * AST + kd]; \
        b1.u = *(const uint4*)&ash[npx1 * AST + kd]; \
        acc[0][0] = __builtin_amdgcn_mfma_f32_16x16x32_f16(a0, b0.h, acc[0][0], 0, 0, 0); \
        acc[0][1] = __builtin_amdgcn_mfma_f32_16x16x32_f16(a0, b1.h, acc[0][1], 0, 0, 0); \
        acc[1][0] = __builtin_amdgcn_mfma_f32_16x16x32_f16(a1, b0.h, acc[1][0], 0, 0, 0); \
        acc[1][1] = __builtin_amdgcn_mfma_f32_16x16x32_f16(a1, b1.h, acc[1][1], 0, 0, 0); }

    // ---- granule loop: segA = sample(g); segB = BWRITE(g+1)|BLOAD(g+2)|MFMA(g) ----
    for (int g = 0; g < NG; ++g) {
        // -- segment A: sample(g) from pband(g) -> ash --
        {
            const float* xg = x + (((size_t)(b * Cn + g * CG)) << 12);
            do_sample(pband, ash, xg, mwp[0], mq[0], mi[0], tid);
            if (tid < 64)
                do_sample(pband, ash, xg, mwp[1], mq[1], mi[1], BDIM + tid);
        }
        __syncthreads();                     // ash(g) ready; pband(g) reads done
        // -- segment B: band-write(g+1) || band-load(g+2) || MFMA(g) --
        if (g + 1 < NG) BWRITE();
        if (g + 2 < NG) BLOAD(g + 2);
        MSTEP(0);
        MSTEP(1);
        MSTEP(2);
        MSTEP(3);
        MSTEP(4);
        __syncthreads();                     // ash reads done; pband(g+1) ready
    }

    // ---- epilogue: transpose via LDS (stride 68, 16B-aligned) -> float4 rows ----
    float* tr = (float*)smem;     // 128 o x 68 = 8704 dw (fits 11424)
    #pragma unroll
    for (int mt = 0; mt < 2; ++mt)
        #pragma unroll
        for (int nt = 0; nt < 2; ++nt)
            #pragma unroll
            for (int r = 0; r < 4; ++r) {
                const int o  = mrow * 32 + mt * 16 + quad * 4 + r;
                const int px = ncol * 32 + nt * 16 + l16;
                tr[o * 68 + px] = acc[mt][nt][r] + bias[o];
            }
    __syncthreads();
    {
        const int orow = tid >> 2, f0 = tid & 3;
        #pragma unroll
        for (int it = 0; it < 4; ++it) {
            const int f = f0 + it * 4;
            const float4 v = *(const float4*)&tr[orow * 68 + (f << 2)];
            *(float4*)&out[(((size_t)b * On + orow) * Hn + h) * Wn + (f << 2)] = v;
        }
    }
#undef BLOAD
#undef BWRITE
#undef MSTEP
}

// ================= fallback: proven R2 fp32 kernel (no d_ws) =================
constexpr int FBD = 256;
constexpr int FB_PXB = 32, FB_CCH = 4, FB_NCT = FB_CCH * KK, FB_MW = KK * FB_PXB;

#define FMA4(A, S, W)                          \
    A.x = fmaf((S).x, (W), A.x);               \
    A.y = fmaf((S).y, (W), A.y);               \
    A.z = fmaf((S).z, (W), A.z);               \
    A.w = fmaf((S).w, (W), A.w);

__global__ __launch_bounds__(FBD, 4)
void dcn_fb_kernel(const float* __restrict__ x,
                   const float* __restrict__ offs,
                   const float* __restrict__ mask,
                   const float* __restrict__ weight,
                   const float* __restrict__ bias,
                   float* __restrict__ out)
{
    __shared__ float wmeta[4 * FB_MW];
    __shared__ int   imeta[4 * FB_MW];
    __shared__ float ssh[FB_NCT * FB_PXB];
    __shared__ float wsh[FB_NCT * On];

    const int tid    = threadIdx.x;
    const int b      = blockIdx.x & 7;
    const int rem    = blockIdx.x >> 3;
    const int h      = rem >> 1;
    const int pxbase = (rem & 1) * FB_PXB;

    for (int e = tid; e < FB_MW; e += FBD) {
        const int t  = e >> 5;
        const int px = e & 31;
        const int pg = pxbase + px;
        const int ty = t / 3, tx = t - ty * 3;
        const float oy = offs[((b * 18 + 2 * t    ) * Hn + h) * Wn + pg];
        const float ox = offs[((b * 18 + 2 * t + 1) * Hn + h) * Wn + pg];
        const float m  = mask[((b * KK + t) * Hn + h) * Wn + pg];
        const float py = (float)(h - PAD + ty) + oy;
        const float qx = (float)(pg - PAD + tx) + ox;
        const float y0 = floorf(py), x0 = floorf(qx);
        const float wy1 = py - y0, wx1 = qx - x0;
        const float wy0 = 1.f - wy1, wx0 = 1.f - wx1;
        const float cw[4] = { wy0 * wx0, wy0 * wx1, wy1 * wx0, wy1 * wx1 };
        #pragma unroll
        for (int k = 0; k < 4; ++k) {
            const float yk = y0 + (float)(k >> 1);
            const float xk = x0 + (float)(k & 1);
            const bool valid = (yk >= 0.f) && (yk <= (float)(Hn - 1)) &&
                               (xk >= 0.f) && (xk <= (float)(Wn - 1));
            const int yc = (int)fminf(fmaxf(yk, 0.f), (float)(Hn - 1));
            const int xc = (int)fminf(fmaxf(xk, 0.f), (float)(Wn - 1));
            wmeta[k * FB_MW + e] = valid ? cw[k] * m : 0.f;
            imeta[k * FB_MW + e] = yc * Wn + xc;
        }
    }
    __syncthreads();

    const int px0 = (tid & 7) << 2;
    const int oo  = (tid >> 3) << 2;

    float4 acc[4];
    #pragma unroll
    for (int j = 0; j < 4; ++j) acc[j] = make_float4(0.f, 0.f, 0.f, 0.f);

    for (int cb = 0; cb < Cn / FB_CCH; ++cb) {
        #pragma unroll
        for (int it = 0; it < (FB_NCT * On) / FBD; ++it) {
            const int e = tid + it * FBD;
            const int r = e >> 7;
            const int o = e & 127;
            wsh[r * On + o] = weight[o * (Cn * KK) + cb * FB_NCT + r];
        }
        for (int e = tid; e < FB_NCT * FB_PXB; e += FBD) {
            const int px = e & 31;
            const int ct = e >> 5;
            const int c  = ct / 9;
            const int mb = (ct - c * 9) * FB_PXB + px;
            const float* xp = x + (((b * Cn) + cb * FB_CCH + c) << 12);
            float v =  wmeta[mb]              * xp[imeta[mb]];
            v = fmaf(wmeta[FB_MW     + mb], xp[imeta[FB_MW     + mb]], v);
            v = fmaf(wmeta[2 * FB_MW + mb], xp[imeta[2 * FB_MW + mb]], v);
            v = fmaf(wmeta[3 * FB_MW + mb], xp[imeta[3 * FB_MW + mb]], v);
            ssh[ct * FB_PXB + px] = v;
        }
        __syncthreads();

        #pragma unroll 6
        for (int ct = 0; ct < FB_NCT; ++ct) {
            const float4 sv = *(const float4*)&ssh[ct * FB_PXB + px0];
            const float4 wa = *(const float4*)&wsh[ct * On + oo];
            FMA4(acc[0], sv, wa.x);
            FMA4(acc[1], sv, wa.y);
            FMA4(acc[2], sv, wa.z);
            FMA4(acc[3], sv, wa.w);
        }
        __syncthreads();
    }

    #pragma unroll
    for (int j = 0; j < 4; ++j) {
        const float bv = bias[oo + j];
        float4 r = acc[j];
        r.x += bv; r.y += bv; r.z += bv; r.w += bv;
        *(float4*)&out[((b * On + oo + j) * Hn + h) * Wn + pxbase + px0] = r;
    }
}

extern "C" void kernel_launch(void* const* d_in, const int* in_sizes, int n_in,
                              void* d_out, int out_size, void* d_ws, size_t ws_size,
                              hipStream_t stream) {
    const float* x      = (const float*)d_in[0];
    const float* offs   = (const float*)d_in[1];
    const float* mask   = (const float*)d_in[2];
    const float* weight = (const float*)d_in[3];
    const float* bias   = (const float*)d_in[4];
    float* out = (float*)d_out;

    if (d_ws != nullptr && ws_size >= WH_BYTES) {
        u16* wh = (u16*)d_ws;
        wprep_kernel<<<dim3(On), dim3(256), 0, stream>>>(weight, wh);
        dcn_mfma_kernel<<<dim3(Bn * Hn), dim3(BDIM), 0, stream>>>(
            x, offs, mask, wh, bias, out);
    } else {
        dcn_fb_kernel<<<dim3(Bn * Hn * 2), dim3(FBD), 0, stream>>>(
            x, offs, mask, weight, bias, out);
    }
}

// Round 13
// 138.072 us; speedup vs baseline: 1.3632x; 1.0162x over previous
//
#include <hip/hip_runtime.h>
#include <math.h>

// DCN v2: B=8, C=128, O=128, H=W=64, k=3, dil=1, dg=1, stride=1, pad=1.
// R21 = FINAL: R12 verbatim (best verified: 138.9 us total, 70.9 us kernel).
// Session ledger: instruction-level fixes (R10-R12) 72->70.9; im2col+GEMM
// split (R13-R15) 180-188 (dead: S round-trip + dispatch overhead); occupancy
// restructures (R16-R20): small-block spills at any VGPR cap (100-110us),
// LDS-trim 3-blocks/CU = null (71us kernel unchanged at 34% occupancy).
// Conclusion: the granule-loop dependency chain (gather->interp->barrier->
// MFMA, 16 convoys, all pipes <35%) is this structure's latency floor at
// ~70us; block concurrency, VALU count, LDS issue count all exonerated by
// measurement.
// Design: 8 waves, full-row blocks (grid 512, 2 blk/CU), f16 data path
// (v_pk_fma_f16 interp, mfma_f32_16x16x32_f16), band double-buffer pipeline
// with MFMA split across both barrier segments, 2-step A prefetch (16 VGPR,
// no spill), AST=84 b128 B-fragments, RST=68 band rows.
constexpr int Bn = 8, Cn = 128, On = 128, Hn = 64, Wn = 64;
constexpr int KK = 9, PAD = 1;
constexpr int BDIM = 512;                 // 8 waves
constexpr int PXB  = 64;                  // full row per block
constexpr int CG = 16, NG = Cn / CG;      // 8 channel granules
constexpr int KG = 160, KTOT = NG * KG;   // 1280 (144 real + 16 pad per granule)
constexpr int BANDH = 11;                 // band rows (h-5 .. h+5)
constexpr int RST  = 68;                  // pband row stride (dwords)
constexpr int XSTP = 756;                 // pband pair stride (dwords), 16B-aligned
constexpr int AST  = 84;                  // ash px stride (dwords), 16B-aligned
constexpr int ME   = KK * PXB;            // 576 sampling elements
constexpr int PB_DW  = 8 * XSTP;          // 6048
constexpr int ASH_DW = PXB * AST;         // 5376
constexpr int SM_DW  = PB_DW + 2 * ASH_DW;// 16800 dwords = 67,200 B
constexpr int BUNITS = BANDH * 128;       // 1408 band load/write units
constexpr size_t WH_BYTES = (size_t)On * KTOT * 2;   // 327,680 B

typedef __attribute__((ext_vector_type(2))) _Float16 h2;      // arithmetic
typedef __attribute__((ext_vector_type(8))) __fp16   f16x8;   // MFMA operand
typedef __attribute__((ext_vector_type(4))) float f32x4;
typedef unsigned short u16;
typedef unsigned int u32;

union UH  { u32 u; h2 h; };
union U4H { uint4 u; f16x8 h; };

__device__ __forceinline__ u32 pkh(float a, float b) {  // low16 = f16(a), RTZ
    union { decltype(__builtin_amdgcn_cvt_pkrtz(0.f, 0.f)) p; u32 u; } t;
    t.p = __builtin_amdgcn_cvt_pkrtz(a, b);
    return t.u;
}
__device__ __forceinline__ h2 bch(u32 w) { UH t; t.u = w; return t.h; }
__device__ __forceinline__ u16 f2h(float f) {           // RNE f32->f16
    union { _Float16 h; u16 u; } v; v.h = (_Float16)f; return v.u;
}

// weight [O][C*9] fp32 -> wh [O][KTOT] f16, k' = g*KG + t*16 + cl.
// One block per o: coalesced reads, LDS bounce, coalesced u32 stores.
__global__ void wprep_kernel(const float* __restrict__ w, u16* __restrict__ wh) {
    __shared__ u32 tmpw[KTOT / 2];
    u16* tmp = (u16*)tmpw;
    const int tid = threadIdx.x, o = blockIdx.x;
    if (tid < 64)    // zero pad slices k=144..159 of each granule (dwords 72..79)
        tmpw[(tid >> 3) * 80 + 72 + (tid & 7)] = 0;
    for (int k = tid; k < Cn * KK; k += 256) {
        const int c = k / 9, t = k - 9 * c;
        tmp[(c >> 4) * KG + t * 16 + (c & 15)] = f2h(w[o * (Cn * KK) + k]);
    }
    __syncthreads();
    u32* dst = (u32*)(wh + (size_t)o * KTOT);
    for (int e = tid; e < KTOT / 2; e += 256) dst[e] = tmpw[e];
}

// sampling of one (tap,px) element for one 16-channel granule.
// wp: 4x u32, each = bilinear weight duplicated as packed f16 pair.
__device__ __forceinline__ void do_sample(const u32* __restrict__ pband,
                                          u32* __restrict__ ashW,
                                          const float* __restrict__ xg,
                                          const uint4 wp, const int2 q,
                                          const int2 ix, const int e)
{
    const int t = e >> 6, px = e & 63;
    u32 avp[8];
    if (!__any((q.x | q.y) < 0)) {           // all corners of wave in band
        const u32* p0 = pband + ix.x;
        const u32* p1 = pband + ix.y;
        const h2 w0 = bch(wp.x), w1 = bch(wp.y), w2 = bch(wp.z), w3 = bch(wp.w);
        #pragma unroll
        for (int c2 = 0; c2 < 8; ++c2) {
            const h2 vt0 = bch(p0[c2 * XSTP]), vt1 = bch(p0[c2 * XSTP + 1]);
            const h2 vb0 = bch(p1[c2 * XSTP]), vb1 = bch(p1[c2 * XSTP + 1]);
            const h2 r = w0 * vt0 + w1 * vt1 + w2 * vb0 + w3 * vb1;
            UH o; o.h = r; avp[c2] = o.u;
        }
    } else {                                  // rare: clamped global reads
        const float fw0 = (float)bch(wp.x)[0], fw1 = (float)bch(wp.y)[0];
        const float fw2 = (float)bch(wp.z)[0], fw3 = (float)bch(wp.w)[0];
        const int qx = q.x < 0 ? ~q.x : q.x;
        const int qy = q.y < 0 ? ~q.y : q.y;
        const int yrx = qx >> 8, yry = qy >> 8;
        const int xx = (qx & 255) - 1, xy = (qy & 255) - 1;
        const int ax0 = max(xx, 0), ax1 = min(xx + 1, Wn - 1);
        const int ay0 = max(xy, 0), ay1 = min(xy + 1, Wn - 1);
        #pragma unroll
        for (int c2 = 0; c2 < 8; ++c2) {
            float v2[2];
            #pragma unroll
            for (int sb = 0; sb < 2; ++sb) {
                const float* gc = xg + ((2 * c2 + sb) << 12);
                const float t0 = gc[yrx * Wn + ax0], t1 = gc[yrx * Wn + ax1];
                const float b0 = gc[yry * Wn + ay0], b1 = gc[yry * Wn + ay1];
                v2[sb] = fmaf(fw0, t0, fmaf(fw1, t1, fmaf(fw2, b0, fw3 * b1)));
            }
            avp[c2] = pkh(v2[0], v2[1]);
        }
    }
    u32* d = ashW + px * AST + t * 8;
    *(uint4*)&d[0] = make_uint4(avp[0], avp[1], avp[2], avp[3]);
    *(uint4*)&d[4] = make_uint4(avp[4], avp[5], avp[6], avp[7]);
}

__global__ __launch_bounds__(BDIM, 4)
void dcn_mfma_kernel(const float* __restrict__ x,
                     const float* __restrict__ offs,
                     const float* __restrict__ mask,
                     const u16*   __restrict__ wh,
                     const float* __restrict__ bias,
                     float* __restrict__ out)
{
    __shared__ __align__(16) u32 smem[SM_DW];   // pband | ash0 | ash1
    u32* const pband = smem;

    const int tid = threadIdx.x;
    const int b   = blockIdx.x & 7;             // batch <-> XCD affinity
    const int h   = blockIdx.x >> 3;
    const int r0  = min(max(h - 5, 0), Hn - BANDH);

    const int s_px4 = tid & 15, s_pair = (tid >> 4) & 7;

    float4 bnda[3], bndb[3];
#define BLOAD(GCH) { \
        _Pragma("unroll") \
        for (int it = 0; it < 3; ++it) { \
            const int u = tid + it * BDIM; \
            if (u < BUNITS) { \
                const int row = u >> 7; \
                const float* bp = x + (((size_t)(b * Cn + (GCH) * CG + 2 * s_pair)) << 12) \
                                  + (r0 + row) * Wn + (s_px4 << 2); \
                bnda[it] = *(const float4*)bp; \
                bndb[it] = *(const float4*)(bp + 4096); \
            } \
        } }
#define BWRITE() { \
        _Pragma("unroll") \
        for (int it = 0; it < 3; ++it) { \
            const int u = tid + it * BDIM; \
            if (u < BUNITS) { \
                const int row = u >> 7; \
                u32* d = &pband[s_pair * XSTP + row * RST + 8 + (s_px4 << 2)]; \
                *(uint4*)d = make_uint4( \
                    pkh(bnda[it].x, bndb[it].x), pkh(bnda[it].y, bndb[it].y), \
                    pkh(bnda[it].z, bndb[it].z), pkh(bnda[it].w, bndb[it].w)); \
            } \
        } }

    BLOAD(0);   // issue granule-0 band loads before meta (latency overlap)

    // ---- meta in registers: packed f16 weights mwp, coord code mq, index mi ----
    uint4 mwp[2]; int2 mq[2]; int2 mi[2];
    #pragma unroll
    for (int it = 0; it < 2; ++it) {
        mwp[it] = make_uint4(0, 0, 0, 0);
        mq[it] = make_int2(r0 << 8, r0 << 8);
        mi[it] = make_int2(7, 7);
        const int e = tid + it * BDIM;
        if (e < ME) {
            const int t = e >> 6, px = e & 63;
            const int ty = t / 3, tx = t - ty * 3;
            const float oy = offs[((b * 18 + 2 * t    ) * Hn + h) * Wn + px];
            const float ox = offs[((b * 18 + 2 * t + 1) * Hn + h) * Wn + px];
            const float m  = mask[((b * KK + t) * Hn + h) * Wn + px];
            const float py = (float)(h - PAD + ty) + oy;
            const float qx = (float)(px - PAD + tx) + ox;
            const float fy = floorf(py), fx = floorf(qx);
            const float wy1 = py - fy, wx1 = qx - fx;
            const float wy0 = 1.f - wy1, wx0 = 1.f - wx1;
            const int y0 = (int)fy, x0 = (int)fx;
            const bool cx0 = (x0 >= 0) && (x0 < Wn);
            const bool cx1 = (x0 >= -1) && (x0 < Wn - 1);
            const float wr[2] = { wy0, wy1 };
            float wout[4]; int qout[2], iout[2];
            #pragma unroll
            for (int j = 0; j < 2; ++j) {
                const int yr = y0 + j;
                const bool rv = (yr >= 0) && (yr < Hn);
                wout[2 * j]     = (rv && cx0) ? wr[j] * wx0 * m : 0.f;
                wout[2 * j + 1] = (rv && cx1) ? wr[j] * wx1 * m : 0.f;
                int qv;
                if (!rv || (!cx0 && !cx1)) qv = r0 << 8;   // junk: w=0, reads pad
                else                       qv = (yr << 8) | (x0 + 1);
                const bool inband = (qv >> 8) >= r0 && (qv >> 8) < r0 + BANDH;
                qout[j] = inband ? qv : ~qv;
                iout[j] = ((qv >> 8) - r0) * RST + (qv & 255) + 7;
            }
            mwp[it] = make_uint4(pkh(wout[0], wout[0]), pkh(wout[1], wout[1]),
                                 pkh(wout[2], wout[2]), pkh(wout[3], wout[3]));
            mq[it] = make_int2(qout[0], qout[1]);
            mi[it] = make_int2(iout[0], iout[1]);
        }
    }

    // ---- zero pband never-written gaps (NaN guard) + ash k-pad chunks ----
    if (tid < 416) {     // per pair: dwords 0..7 and 68r+72..75 (r=0..10)
        const int pair = tid / 52, j = tid - pair * 52;
        const int off = (j < 8) ? j : RST * ((j - 8) >> 2) + 72 + ((j - 8) & 3);
        pband[pair * XSTP + off] = 0;
    }
    #pragma unroll
    for (int it = 0; it < 2; ++it) {
        const int u = tid + it * BDIM;        // 0..1023
        smem[PB_DW + (u >> 9) * ASH_DW + ((u & 511) >> 3) * AST + 72 + (u & 7)] = 0;
    }

    BWRITE();       // band 0 -> pband
    BLOAD(1);       // issue granule-1 band loads (consumed after next barrier)
    __syncthreads();

    const int wv = tid >> 6, ln = tid & 63, quad = ln >> 4, l16 = ln & 15;
    const int mrow = wv >> 1, ncol = wv & 1;            // 4x2 wave tiling
    const u16* wrow0 = wh + (size_t)(mrow * 32 + l16) * KTOT;
    const int npx0 = ncol * 32 + l16, npx1 = npx0 + 16;

    // ---- sample granule 0 -> ash[0] ----
    {
        const float* xg = x + (((size_t)(b * Cn)) << 12);
        do_sample(pband, smem + PB_DW, xg, mwp[0], mq[0], mi[0], tid);
        if (tid < 64)
            do_sample(pband, smem + PB_DW, xg, mwp[1], mq[1], mi[1], BDIM + tid);
    }
    __syncthreads();

    f32x4 acc[2][2];
    #pragma unroll
    for (int mt = 0; mt < 2; ++mt)
        #pragma unroll
        for (int nt = 0; nt < 2; ++nt) acc[mt][nt] = (f32x4){0.f, 0.f, 0.f, 0.f};

    f16x8 pa0[2], pa1[2];     // prefetched A fragments for steps 0,1 (16 VGPR)
#define APRE(GG) { const int kgp = (GG) * KG + quad * 8; \
        pa0[0] = *(const f16x8*)(wrow0 + kgp); \
        pa1[0] = *(const f16x8*)(wrow0 + 16 * KTOT + kgp); \
        pa0[1] = *(const f16x8*)(wrow0 + kgp + 32); \
        pa1[1] = *(const f16x8*)(wrow0 + 16 * KTOT + kgp + 32); }
    APRE(0);

#define MSTEP_PRE(S) { \
        const int kd = (S) * 16 + quad * 4; \
        U4H b0, b1; \
        b0.u = *(const uint4*)&ad[npx0 * AST + kd]; \
        b1.u = *(const uint4*)&ad[npx1 * AST + kd]; \
        acc[0][0] = __builtin_amdgcn_mfma_f32_16x16x32_f16(pa0[S], b0.h, acc[0][0], 0, 0, 0); \
        acc[0][1] = __builtin_amdgcn_mfma_f32_16x16x32_f16(pa0[S], b1.h, acc[0][1], 0, 0, 0); \
        acc[1][0] = __builtin_amdgcn_mfma_f32_16x16x32_f16(pa1[S], b0.h, acc[1][0], 0, 0, 0); \
        acc[1][1] = __builtin_amdgcn_mfma_f32_16x16x32_f16(pa1[S], b1.h, acc[1][1], 0, 0, 0); }

#define MSTEP_LD(S) { \
        const int kg = g * KG + (S) * 32 + quad * 8; \
        const f16x8 a0 = *(const f16x8*)(wrow0 + kg); \
        const f16x8 a1 = *(const f16x8*)(wrow0 + 16 * KTOT + kg); \
        const int kd = (S) * 16 + quad * 4; \
        U4H b0, b1; \
        b0.u = *(const uint4*)&ad[npx0 * AST + kd]; \
        b1.u = *(const uint4*)&ad[npx1 * AST + kd]; \
        acc[0][0] = __builtin_amdgcn_mfma_f32_16x16x32_f16(a0, b0.h, acc[0][0], 0, 0, 0); \
        acc[0][1] = __builtin_amdgcn_mfma_f32_16x16x32_f16(a0, b1.h, acc[0][1], 0, 0, 0); \
        acc[1][0] = __builtin_amdgcn_mfma_f32_16x16x32_f16(a1, b0.h, acc[1][0], 0, 0, 0); \
        acc[1][1] = __builtin_amdgcn_mfma_f32_16x16x32_f16(a1, b1.h, acc[1][1], 0, 0, 0); }

    // ---- pipelined granule loop: 2 barriers/granule, MFMA in BOTH segments ----
    for (int g = 0; g < NG; ++g) {
        const u32* ad = smem + PB_DW + (g & 1) * ASH_DW;        // MFMA(g) source
        u32* ashN     = smem + PB_DW + ((g + 1) & 1) * ASH_DW;  // sample(g+1) dest
        // -- segment B: band-write(g+1) || MFMA(g) steps 0-1 --
        if (g + 1 < NG) BWRITE();
        MSTEP_PRE(0);
        MSTEP_PRE(1);
        __syncthreads();                                         // pband(g+1) ready
        // -- segment A: band-load(g+2) || sample(g+1) || MFMA(g) steps 2-4 --
        if (g + 2 < NG) BLOAD(g + 2);
        if (g + 1 < NG) {
            const float* xg = x + (((size_t)(b * Cn + (g + 1) * CG)) << 12);
            do_sample(pband, ashN, xg, mwp[0], mq[0], mi[0], tid);
            if (tid < 64)
                do_sample(pband, ashN, xg, mwp[1], mq[1], mi[1], BDIM + tid);
        }
        MSTEP_LD(2);
        MSTEP_LD(3);
        MSTEP_LD(4);
        if (g + 1 < NG) APRE(g + 1);
        __syncthreads();    // ash[(g+1)&1] ready; ash[g&1]/pband reads drained
    }

    // ---- epilogue: transpose via LDS (stride 68, 16B-aligned) -> float4 rows ----
    float* tr = (float*)smem;     // 128 o x 64 px, overlays pband+ash0 (safe)
    #pragma unroll
    for (int mt = 0; mt < 2; ++mt)
        #pragma unroll
        for (int nt = 0; nt < 2; ++nt)
            #pragma unroll
            for (int r = 0; r < 4; ++r) {
                const int o  = mrow * 32 + mt * 16 + quad * 4 + r;
                const int px = ncol * 32 + nt * 16 + l16;
                tr[o * 68 + px] = acc[mt][nt][r] + bias[o];
            }
    __syncthreads();
    {
        const int orow = tid >> 2, f0 = tid & 3;
        #pragma unroll
        for (int it = 0; it < 4; ++it) {
            const int f = f0 + it * 4;
            const float4 v = *(const float4*)&tr[orow * 68 + (f << 2)];
            *(float4*)&out[(((size_t)b * On + orow) * Hn + h) * Wn + (f << 2)] = v;
        }
    }
#undef BLOAD
#undef BWRITE
#undef APRE
#undef MSTEP_PRE
#undef MSTEP_LD
}

// ================= fallback: proven R2 fp32 kernel (no d_ws) =================
constexpr int FBD = 256;
constexpr int FB_PXB = 32, FB_CCH = 4, FB_NCT = FB_CCH * KK, FB_MW = KK * FB_PXB;

#define FMA4(A, S, W)                          \
    A.x = fmaf((S).x, (W), A.x);               \
    A.y = fmaf((S).y, (W), A.y);               \
    A.z = fmaf((S).z, (W), A.z);               \
    A.w = fmaf((S).w, (W), A.w);

__global__ __launch_bounds__(FBD, 4)
void dcn_fb_kernel(const float* __restrict__ x,
                   const float* __restrict__ offs,
                   const float* __restrict__ mask,
                   const float* __restrict__ weight,
                   const float* __restrict__ bias,
                   float* __restrict__ out)
{
    __shared__ float wmeta[4 * FB_MW];
    __shared__ int   imeta[4 * FB_MW];
    __shared__ float ssh[FB_NCT * FB_PXB];
    __shared__ float wsh[FB_NCT * On];

    const int tid    = threadIdx.x;
    const int b      = blockIdx.x & 7;
    const int rem    = blockIdx.x >> 3;
    const int h      = rem >> 1;
    const int pxbase = (rem & 1) * FB_PXB;

    for (int e = tid; e < FB_MW; e += FBD) {
        const int t  = e >> 5;
        const int px = e & 31;
        const int pg = pxbase + px;
        const int ty = t / 3, tx = t - ty * 3;
        const float oy = offs[((b * 18 + 2 * t    ) * Hn + h) * Wn + pg];
        const float ox = offs[((b * 18 + 2 * t + 1) * Hn + h) * Wn + pg];
        const float m  = mask[((b * KK + t) * Hn + h) * Wn + pg];
        const float py = (float)(h - PAD + ty) + oy;
        const float qx = (float)(pg - PAD + tx) + ox;
        const float y0 = floorf(py), x0 = floorf(qx);
        const float wy1 = py - y0, wx1 = qx - x0;
        const float wy0 = 1.f - wy1, wx0 = 1.f - wx1;
        const float cw[4] = { wy0 * wx0, wy0 * wx1, wy1 * wx0, wy1 * wx1 };
        #pragma unroll
        for (int k = 0; k < 4; ++k) {
            const float yk = y0 + (float)(k >> 1);
            const float xk = x0 + (float)(k & 1);
            const bool valid = (yk >= 0.f) && (yk <= (float)(Hn - 1)) &&
                               (xk >= 0.f) && (xk <= (float)(Wn - 1));
            const int yc = (int)fminf(fmaxf(yk, 0.f), (float)(Hn - 1));
            const int xc = (int)fminf(fmaxf(xk, 0.f), (float)(Wn - 1));
            wmeta[k * FB_MW + e] = valid ? cw[k] * m : 0.f;
            imeta[k * FB_MW + e] = yc * Wn + xc;
        }
    }
    __syncthreads();

    const int px0 = (tid & 7) << 2;
    const int oo  = (tid >> 3) << 2;

    float4 acc[4];
    #pragma unroll
    for (int j = 0; j < 4; ++j) acc[j] = make_float4(0.f, 0.f, 0.f, 0.f);

    for (int cb = 0; cb < Cn / FB_CCH; ++cb) {
        #pragma unroll
        for (int it = 0; it < (FB_NCT * On) / FBD; ++it) {
            const int e = tid + it * FBD;
            const int r = e >> 7;
            const int o = e & 127;
            wsh[r * On + o] = weight[o * (Cn * KK) + cb * FB_NCT + r];
        }
        for (int e = tid; e < FB_NCT * FB_PXB; e += FBD) {
            const int px = e & 31;
            const int ct = e >> 5;
            const int c  = ct / 9;
            const int mb = (ct - c * 9) * FB_PXB + px;
            const float* xp = x + (((b * Cn) + cb * FB_CCH + c) << 12);
            float v =  wmeta[mb]              * xp[imeta[mb]];
            v = fmaf(wmeta[FB_MW     + mb], xp[imeta[FB_MW     + mb]], v);
            v = fmaf(wmeta[2 * FB_MW + mb], xp[imeta[2 * FB_MW + mb]], v);
            v = fmaf(wmeta[3 * FB_MW + mb], xp[imeta[3 * FB_MW + mb]], v);
            ssh[ct * FB_PXB + px] = v;
        }
        __syncthreads();

        #pragma unroll 6
        for (int ct = 0; ct < FB_NCT; ++ct) {
            const float4 sv = *(const float4*)&ssh[ct * FB_PXB + px0];
            const float4 wa = *(const float4*)&wsh[ct * On + oo];
            FMA4(acc[0], sv, wa.x);
            FMA4(acc[1], sv, wa.y);
            FMA4(acc[2], sv, wa.z);
            FMA4(acc[3], sv, wa.w);
        }
        __syncthreads();
    }

    #pragma unroll
    for (int j = 0; j < 4; ++j) {
        const float bv = bias[oo + j];
        float4 r = acc[j];
        r.x += bv; r.y += bv; r.z += bv; r.w += bv;
        *(float4*)&out[((b * On + oo + j) * Hn + h) * Wn + pxbase + px0] = r;
    }
}

extern "C" void kernel_launch(void* const* d_in, const int* in_sizes, int n_in,
                              void* d_out, int out_size, void* d_ws, size_t ws_size,
                              hipStream_t stream) {
    const float* x      = (const float*)d_in[0];
    const float* offs   = (const float*)d_in[1];
    const float* mask   = (const float*)d_in[2];
    const float* weight = (const float*)d_in[3];
    const float* bias   = (const float*)d_in[4];
    float* out = (float*)d_out;

    if (d_ws != nullptr && ws_size >= WH_BYTES) {
        u16* wh = (u16*)d_ws;
        wprep_kernel<<<dim3(On), dim3(256), 0, stream>>>(weight, wh);
        dcn_mfma_kernel<<<dim3(Bn * Hn), dim3(BDIM), 0, stream>>>(
            x, offs, mask, wh, bias, out);
    } else {
        dcn_fb_kernel<<<dim3(Bn * Hn * 2), dim3(FBD), 0, stream>>>(
            x, offs, mask, weight, bias, out);
    }
}